// Round 1
// baseline (1626.544 us; speedup 1.0000x reference)
//
#include <hip/hip_runtime.h>

#define NN 50000
#define NE 800000

// ---------------- degree count / inverse ----------------
__global__ void count_kernel(const int* __restrict__ dst, float* __restrict__ cnt) {
    int i = blockIdx.x * blockDim.x + threadIdx.x;
    if (i < NE) atomicAdd(&cnt[dst[i]], 1.0f);
}

__global__ void invert_kernel(float* __restrict__ cnt) {
    int i = blockIdx.x * blockDim.x + threadIdx.x;
    if (i < NN) cnt[i] = 1.0f / fmaxf(cnt[i], 1.0f);
}

// ---------------- dense: out[v][o] = dot(x[v], W[o]) (+ bl[o]) ----------------
// W is [O][K] row-major (PyTorch-style). Block = 256 threads, NT nodes per block.
template<int K, int O, int NT, bool BIAS>
__global__ __launch_bounds__(256) void gemm1_kernel(
    const float* __restrict__ x, const float* __restrict__ W,
    const float* __restrict__ bl, float* __restrict__ out) {
    __shared__ float WT[K][O];   // transposed so lanes (o) read consecutive
    __shared__ float xt[NT][K];
    const int tid = threadIdx.x;
    for (int idx = tid; idx < K * O; idx += 256) {
        int kk = idx / O, oo = idx - kk * O;
        WT[kk][oo] = W[oo * K + kk];
    }
    const int v0 = blockIdx.x * NT;
    for (int idx = tid; idx < NT * K; idx += 256) {
        int r = idx / K, c = idx - r * K;
        int v = v0 + r;
        xt[r][c] = (v < NN) ? x[(size_t)v * K + c] : 0.0f;
    }
    __syncthreads();

    const int o = tid % O;
    const int g = tid / O;
    constexpr int GR = 256 / O;   // thread groups
    constexpr int JN = NT / GR;   // nodes per thread
    float acc[JN];
    float b = 0.0f;
    if constexpr (BIAS) b = bl[o];
#pragma unroll
    for (int j = 0; j < JN; ++j) acc[j] = b;

    for (int k = 0; k < K; k += 4) {
        float w0 = WT[k][o], w1 = WT[k + 1][o], w2 = WT[k + 2][o], w3 = WT[k + 3][o];
#pragma unroll
        for (int j = 0; j < JN; ++j) {
            const float4 xv = *reinterpret_cast<const float4*>(&xt[g * JN + j][k]);
            acc[j] += xv.x * w0 + xv.y * w1 + xv.z * w2 + xv.w * w3;
        }
    }
#pragma unroll
    for (int j = 0; j < JN; ++j) {
        int v = v0 + g * JN + j;
        if (v < NN) out[(size_t)v * O + o] = acc[j];
    }
}

// ---------------- dense fused (layer 2): out = relu((s*inv)@WlT + x@WrT + bl) ----------------
template<int K, int O, int NT>
__global__ __launch_bounds__(256) void gemm2_kernel(
    const float* __restrict__ s, const float* __restrict__ inv,
    const float* __restrict__ x,
    const float* __restrict__ Wl, const float* __restrict__ Wr,
    const float* __restrict__ bl, float* __restrict__ out) {
    __shared__ float WlT[K][O];
    __shared__ float WrT[K][O];
    __shared__ float st[NT][K];
    __shared__ float xt[NT][K];
    const int tid = threadIdx.x;
    for (int idx = tid; idx < K * O; idx += 256) {
        int kk = idx / O, oo = idx - kk * O;
        WlT[kk][oo] = Wl[oo * K + kk];
        WrT[kk][oo] = Wr[oo * K + kk];
    }
    const int v0 = blockIdx.x * NT;
    for (int idx = tid; idx < NT * K; idx += 256) {
        int r = idx / K, c = idx - r * K;
        int v = v0 + r;
        if (v < NN) {
            st[r][c] = s[(size_t)v * K + c] * inv[v];
            xt[r][c] = x[(size_t)v * K + c];
        } else {
            st[r][c] = 0.0f;
            xt[r][c] = 0.0f;
        }
    }
    __syncthreads();

    const int o = tid % O;
    const int g = tid / O;
    constexpr int GR = 256 / O;
    constexpr int JN = NT / GR;
    float acc[JN];
    float b = bl[o];
#pragma unroll
    for (int j = 0; j < JN; ++j) acc[j] = b;

    for (int k = 0; k < K; k += 4) {
        float l0 = WlT[k][o], l1 = WlT[k + 1][o], l2 = WlT[k + 2][o], l3 = WlT[k + 3][o];
        float r0 = WrT[k][o], r1 = WrT[k + 1][o], r2 = WrT[k + 2][o], r3 = WrT[k + 3][o];
#pragma unroll
        for (int j = 0; j < JN; ++j) {
            const float4 sv = *reinterpret_cast<const float4*>(&st[g * JN + j][k]);
            const float4 xv = *reinterpret_cast<const float4*>(&xt[g * JN + j][k]);
            acc[j] += sv.x * l0 + sv.y * l1 + sv.z * l2 + sv.w * l3;
            acc[j] += xv.x * r0 + xv.y * r1 + xv.z * r2 + xv.w * r3;
        }
    }
#pragma unroll
    for (int j = 0; j < JN; ++j) {
        int v = v0 + g * JN + j;
        if (v < NN) out[(size_t)v * O + o] = fmaxf(acc[j], 0.0f);
    }
}

// ---------------- edge scatter-add: out[dst] += y[src] * (SCALE ? inv[dst] : 1) ----------------
template<int D, bool SCALE>
__global__ void scatter_kernel(const float* __restrict__ y,
                               const int* __restrict__ src, const int* __restrict__ dst,
                               const float* __restrict__ inv, float* __restrict__ out) {
    const int nw = (gridDim.x * blockDim.x) >> 6;
    const int wid = (blockIdx.x * blockDim.x + threadIdx.x) >> 6;
    const int lane = threadIdx.x & 63;
    for (int e = wid; e < NE; e += nw) {
        const int sv = src[e];
        const int dv = dst[e];
        float sc = 1.0f;
        if constexpr (SCALE) sc = inv[dv];
#pragma unroll
        for (int d = lane; d < D; d += 64) {
            atomicAdd(&out[(size_t)dv * D + d], y[(size_t)sv * D + d] * sc);
        }
    }
}

// ---------------- elementwise relu (in place, float4) ----------------
__global__ void relu_kernel(float* __restrict__ p, int n4) {
    int i = blockIdx.x * blockDim.x + threadIdx.x;
    if (i < n4) {
        float4 v = reinterpret_cast<float4*>(p)[i];
        v.x = fmaxf(v.x, 0.0f);
        v.y = fmaxf(v.y, 0.0f);
        v.z = fmaxf(v.z, 0.0f);
        v.w = fmaxf(v.w, 0.0f);
        reinterpret_cast<float4*>(p)[i] = v;
    }
}

extern "C" void kernel_launch(void* const* d_in, const int* in_sizes, int n_in,
                              void* d_out, int out_size, void* d_ws, size_t ws_size,
                              hipStream_t stream) {
    const float* x   = (const float*)d_in[0];
    const int*   eix = (const int*)d_in[1];
    const float* Wl1 = (const float*)d_in[2];
    const float* bl1 = (const float*)d_in[3];
    const float* Wr1 = (const float*)d_in[4];
    const float* Wl2 = (const float*)d_in[5];
    const float* bl2 = (const float*)d_in[6];
    const float* Wr2 = (const float*)d_in[7];
    const float* Wl3 = (const float*)d_in[8];
    const float* bl3 = (const float*)d_in[9];
    const float* Wr3 = (const float*)d_in[10];
    const float* Wl4 = (const float*)d_in[11];
    const float* bl4 = (const float*)d_in[12];
    const float* Wr4 = (const float*)d_in[13];
    float* out = (float*)d_out;

    const int* src = eix;        // edge_index[0]
    const int* dst = eix + NE;   // edge_index[1]

    // workspace layout (floats)
    char* ws = (char*)d_ws;
    float* inv = (float*)ws;                         // [NN], also used as cnt
    float* G1  = (float*)(ws + 204800);              // [NN*128] projected msgs / L2 agg
    float* H13 = G1 + (size_t)NN * 128;              // [NN*128] h1 (64-wide) then h3
    float* H2  = H13 + (size_t)NN * 128;             // [NN*128] h2

    // degree counts -> inverse
    hipMemsetAsync(inv, 0, NN * sizeof(float), stream);
    count_kernel<<<(NE + 255) / 256, 256, 0, stream>>>(dst, inv);
    invert_kernel<<<(NN + 255) / 256, 256, 0, stream>>>(inv);

    // ---- Layer 1 (128 -> 64, project-first, fused scatter into output) ----
    gemm1_kernel<128, 64, 32, false><<<1563, 256, 0, stream>>>(x, Wl1, nullptr, G1);
    gemm1_kernel<128, 64, 32, true ><<<1563, 256, 0, stream>>>(x, Wr1, bl1, H13);
    scatter_kernel<64, true><<<1024, 256, 0, stream>>>(G1, src, dst, inv, H13);
    relu_kernel<<<(NN * 64 / 4 + 255) / 256, 256, 0, stream>>>(H13, NN * 64 / 4);

    // ---- Layer 2 (64 -> 128, aggregate-first) ----
    hipMemsetAsync(G1, 0, (size_t)NN * 64 * sizeof(float), stream);
    scatter_kernel<64, false><<<1024, 256, 0, stream>>>(H13, src, dst, inv, G1);
    gemm2_kernel<64, 128, 16><<<3125, 256, 0, stream>>>(G1, inv, H13, Wl2, Wr2, bl2, H2);

    // ---- Layer 3 (128 -> 128, project-first) ----
    gemm1_kernel<128, 128, 16, false><<<3125, 256, 0, stream>>>(H2, Wl3, nullptr, G1);
    gemm1_kernel<128, 128, 16, true ><<<3125, 256, 0, stream>>>(H2, Wr3, bl3, H13);
    scatter_kernel<128, true><<<1024, 256, 0, stream>>>(G1, src, dst, inv, H13);
    relu_kernel<<<(NN * 128 / 4 + 255) / 256, 256, 0, stream>>>(H13, NN * 128 / 4);

    // ---- Layer 4 (128 -> 64, project-first, scatter straight into d_out) ----
    gemm1_kernel<128, 64, 32, false><<<1563, 256, 0, stream>>>(H13, Wl4, nullptr, G1);
    gemm1_kernel<128, 64, 32, true ><<<1563, 256, 0, stream>>>(H13, Wr4, bl4, out);
    scatter_kernel<64, true><<<1024, 256, 0, stream>>>(G1, src, dst, inv, out);
}

// Round 2
// 1014.932 us; speedup vs baseline: 1.6026x; 1.6026x over previous
//
#include <hip/hip_runtime.h>

#define NN 50000
#define NE 800000

// ---------------- CSR build: count, scan(+inv), bucket fill ----------------
__global__ void count_kernel(const int* __restrict__ dst, int* __restrict__ cnt) {
    int i = blockIdx.x * blockDim.x + threadIdx.x;
    if (i < NE) atomicAdd(&cnt[dst[i]], 1);
}

__global__ __launch_bounds__(1024) void scan_kernel(const int* __restrict__ cnt,
                                                    int* __restrict__ off,
                                                    int* __restrict__ cursor,
                                                    float* __restrict__ inv) {
    __shared__ int ps[1024];
    const int t = threadIdx.x;
    const int C = (NN + 1023) / 1024;   // 49 elems per thread
    const int base = t * C;
    int s = 0;
    for (int i = 0; i < C; ++i) {
        int idx = base + i;
        if (idx < NN) s += cnt[idx];
    }
    ps[t] = s;
    __syncthreads();
    // Hillis-Steele inclusive scan over 1024 partials
    for (int d = 1; d < 1024; d <<= 1) {
        int v = (t >= d) ? ps[t - d] : 0;
        __syncthreads();
        ps[t] += v;
        __syncthreads();
    }
    int run = (t == 0) ? 0 : ps[t - 1];
    for (int i = 0; i < C; ++i) {
        int idx = base + i;
        if (idx < NN) {
            int c = cnt[idx];
            off[idx] = run;
            cursor[idx] = run;
            inv[idx] = 1.0f / (float)max(c, 1);
            run += c;
        }
    }
}

__global__ void fill_kernel(const int* __restrict__ src, const int* __restrict__ dst,
                            int* __restrict__ cursor, int* __restrict__ srcs) {
    int e = blockIdx.x * blockDim.x + threadIdx.x;
    if (e < NE) {
        int p = atomicAdd(&cursor[dst[e]], 1);
        srcs[p] = src[e];
    }
}

// ---------------- pull-gather mean aggregation, one wave per dst node ----------------
// MODE: 0 = out = mean ; 1 = out = relu(pre + mean) ; 2 = out = pre + mean
template<int D, int MODE>
__global__ __launch_bounds__(256) void gather_kernel(
    const float* __restrict__ y, const int* __restrict__ srcs,
    const int* __restrict__ off, const int* __restrict__ cnt,
    const float* __restrict__ inv, const float* __restrict__ pre,
    float* __restrict__ out) {
    const int w = (blockIdx.x * blockDim.x + threadIdx.x) >> 6;
    const int lane = threadIdx.x & 63;
    if (w >= NN) return;
    const int o = __builtin_amdgcn_readfirstlane(off[w]);
    const int n = __builtin_amdgcn_readfirstlane(cnt[w]);
    float a0 = 0.0f, a1 = 0.0f;
    int i = 0;
    for (; i + 4 <= n; i += 4) {
        int sv[4];
#pragma unroll
        for (int u = 0; u < 4; ++u) sv[u] = srcs[o + i + u];
#pragma unroll
        for (int u = 0; u < 4; ++u) {
            a0 += y[(size_t)sv[u] * D + lane];
            if constexpr (D == 128) a1 += y[(size_t)sv[u] * D + 64 + lane];
        }
    }
    for (; i < n; ++i) {
        int s = srcs[o + i];
        a0 += y[(size_t)s * D + lane];
        if constexpr (D == 128) a1 += y[(size_t)s * D + 64 + lane];
    }
    const float iv = inv[w];
    const size_t b = (size_t)w * D + lane;
    float r0 = a0 * iv;
    if constexpr (MODE != 0) r0 += pre[b];
    if constexpr (MODE == 1) r0 = fmaxf(r0, 0.0f);
    out[b] = r0;
    if constexpr (D == 128) {
        float r1 = a1 * iv;
        if constexpr (MODE != 0) r1 += pre[b + 64];
        if constexpr (MODE == 1) r1 = fmaxf(r1, 0.0f);
        out[b + 64] = r1;
    }
}

// ---------------- dense: out[v][o] = dot(x[v], W[o]) (+ bl[o]) ----------------
template<int K, int O, int NT, bool BIAS>
__global__ __launch_bounds__(256) void gemm1_kernel(
    const float* __restrict__ x, const float* __restrict__ W,
    const float* __restrict__ bl, float* __restrict__ out) {
    __shared__ float WT[K][O];
    __shared__ float xt[NT][K];
    const int tid = threadIdx.x;
    for (int idx = tid; idx < K * O; idx += 256) {
        int kk = idx / O, oo = idx - kk * O;
        WT[kk][oo] = W[oo * K + kk];
    }
    const int v0 = blockIdx.x * NT;
    for (int idx = tid; idx < NT * K; idx += 256) {
        int r = idx / K, c = idx - r * K;
        int v = v0 + r;
        xt[r][c] = (v < NN) ? x[(size_t)v * K + c] : 0.0f;
    }
    __syncthreads();

    const int o = tid % O;
    const int g = tid / O;
    constexpr int GR = 256 / O;
    constexpr int JN = NT / GR;
    float acc[JN];
    float b = 0.0f;
    if constexpr (BIAS) b = bl[o];
#pragma unroll
    for (int j = 0; j < JN; ++j) acc[j] = b;

    for (int k = 0; k < K; k += 4) {
        float w0 = WT[k][o], w1 = WT[k + 1][o], w2 = WT[k + 2][o], w3 = WT[k + 3][o];
#pragma unroll
        for (int j = 0; j < JN; ++j) {
            const float4 xv = *reinterpret_cast<const float4*>(&xt[g * JN + j][k]);
            acc[j] += xv.x * w0 + xv.y * w1 + xv.z * w2 + xv.w * w3;
        }
    }
#pragma unroll
    for (int j = 0; j < JN; ++j) {
        int v = v0 + g * JN + j;
        if (v < NN) out[(size_t)v * O + o] = acc[j];
    }
}

// ---------------- fused layer-2 dense: out = relu(s@WlT + x@WrT + bl), s already mean ----------------
template<int K, int O, int NT>
__global__ __launch_bounds__(256) void gemm2_kernel(
    const float* __restrict__ s, const float* __restrict__ x,
    const float* __restrict__ Wl, const float* __restrict__ Wr,
    const float* __restrict__ bl, float* __restrict__ out) {
    __shared__ float WlT[K][O];
    __shared__ float WrT[K][O];
    __shared__ float st[NT][K];
    __shared__ float xt[NT][K];
    const int tid = threadIdx.x;
    for (int idx = tid; idx < K * O; idx += 256) {
        int kk = idx / O, oo = idx - kk * O;
        WlT[kk][oo] = Wl[oo * K + kk];
        WrT[kk][oo] = Wr[oo * K + kk];
    }
    const int v0 = blockIdx.x * NT;
    for (int idx = tid; idx < NT * K; idx += 256) {
        int r = idx / K, c = idx - r * K;
        int v = v0 + r;
        if (v < NN) {
            st[r][c] = s[(size_t)v * K + c];
            xt[r][c] = x[(size_t)v * K + c];
        } else {
            st[r][c] = 0.0f;
            xt[r][c] = 0.0f;
        }
    }
    __syncthreads();

    const int o = tid % O;
    const int g = tid / O;
    constexpr int GR = 256 / O;
    constexpr int JN = NT / GR;
    float acc[JN];
    float b = bl[o];
#pragma unroll
    for (int j = 0; j < JN; ++j) acc[j] = b;

    for (int k = 0; k < K; k += 4) {
        float l0 = WlT[k][o], l1 = WlT[k + 1][o], l2 = WlT[k + 2][o], l3 = WlT[k + 3][o];
        float r0 = WrT[k][o], r1 = WrT[k + 1][o], r2 = WrT[k + 2][o], r3 = WrT[k + 3][o];
#pragma unroll
        for (int j = 0; j < JN; ++j) {
            const float4 sv = *reinterpret_cast<const float4*>(&st[g * JN + j][k]);
            const float4 xv = *reinterpret_cast<const float4*>(&xt[g * JN + j][k]);
            acc[j] += sv.x * l0 + sv.y * l1 + sv.z * l2 + sv.w * l3;
            acc[j] += xv.x * r0 + xv.y * r1 + xv.z * r2 + xv.w * r3;
        }
    }
#pragma unroll
    for (int j = 0; j < JN; ++j) {
        int v = v0 + g * JN + j;
        if (v < NN) out[(size_t)v * O + o] = fmaxf(acc[j], 0.0f);
    }
}

extern "C" void kernel_launch(void* const* d_in, const int* in_sizes, int n_in,
                              void* d_out, int out_size, void* d_ws, size_t ws_size,
                              hipStream_t stream) {
    const float* x   = (const float*)d_in[0];
    const int*   eix = (const int*)d_in[1];
    const float* Wl1 = (const float*)d_in[2];
    const float* bl1 = (const float*)d_in[3];
    const float* Wr1 = (const float*)d_in[4];
    const float* Wl2 = (const float*)d_in[5];
    const float* bl2 = (const float*)d_in[6];
    const float* Wr2 = (const float*)d_in[7];
    const float* Wl3 = (const float*)d_in[8];
    const float* bl3 = (const float*)d_in[9];
    const float* Wr3 = (const float*)d_in[10];
    const float* Wl4 = (const float*)d_in[11];
    const float* bl4 = (const float*)d_in[12];
    const float* Wr4 = (const float*)d_in[13];
    float* out = (float*)d_out;

    const int* src = eix;        // edge_index[0]
    const int* dst = eix + NE;   // edge_index[1]

    // workspace layout
    char* ws = (char*)d_ws;
    int*   cnt    = (int*)ws;                       // [NN]
    int*   off    = cnt + NN;                       // [NN]
    int*   cursor = off + NN;                       // [NN]
    float* inv    = (float*)(cursor + NN);          // [NN]
    int*   srcs   = (int*)(inv + NN);               // [NE]
    float* G1  = (float*)(srcs + NE);               // [NN*128]
    float* H13 = G1 + (size_t)NN * 128;             // [NN*128]
    float* H2  = H13 + (size_t)NN * 128;            // [NN*128]

    // ---- CSR build (per call, deterministic work) ----
    hipMemsetAsync(cnt, 0, NN * sizeof(int), stream);
    count_kernel<<<(NE + 255) / 256, 256, 0, stream>>>(dst, cnt);
    scan_kernel<<<1, 1024, 0, stream>>>(cnt, off, cursor, inv);
    fill_kernel<<<(NE + 255) / 256, 256, 0, stream>>>(src, dst, cursor, srcs);

    // ---- Layer 1 (128 -> 64, project-first) ----
    gemm1_kernel<128, 64, 32, false><<<1563, 256, 0, stream>>>(x, Wl1, nullptr, G1);
    gemm1_kernel<128, 64, 32, true ><<<1563, 256, 0, stream>>>(x, Wr1, bl1, H13);
    gather_kernel<64, 1><<<12500, 256, 0, stream>>>(G1, srcs, off, cnt, inv, H13, H13);

    // ---- Layer 2 (64 -> 128, aggregate-first) ----
    gather_kernel<64, 0><<<12500, 256, 0, stream>>>(H13, srcs, off, cnt, inv, nullptr, G1);
    gemm2_kernel<64, 128, 16><<<3125, 256, 0, stream>>>(G1, H13, Wl2, Wr2, bl2, H2);

    // ---- Layer 3 (128 -> 128, project-first) ----
    gemm1_kernel<128, 128, 16, false><<<3125, 256, 0, stream>>>(H2, Wl3, nullptr, G1);
    gemm1_kernel<128, 128, 16, true ><<<3125, 256, 0, stream>>>(H2, Wr3, bl3, H13);
    gather_kernel<128, 1><<<12500, 256, 0, stream>>>(G1, srcs, off, cnt, inv, H13, H13);

    // ---- Layer 4 (128 -> 64, project-first, into d_out) ----
    gemm1_kernel<128, 64, 32, false><<<1563, 256, 0, stream>>>(H13, Wl4, nullptr, G1);
    gemm1_kernel<128, 64, 32, true ><<<1563, 256, 0, stream>>>(H13, Wr4, bl4, out);
    gather_kernel<64, 2><<<12500, 256, 0, stream>>>(G1, srcs, off, cnt, inv, out, out);
}

// Round 3
// 951.046 us; speedup vs baseline: 1.7103x; 1.0672x over previous
//
#include <hip/hip_runtime.h>

#define NN 50000
#define NE 800000
#define NPW 32
#define NSTRIPES ((NN + NPW - 1) / NPW)   // 1563

__device__ __forceinline__ int uni(int v) { return __builtin_amdgcn_readfirstlane(v); }

// ---------------- CSR build: count, scan(+inv), bucket fill ----------------
__global__ void count_kernel(const int* __restrict__ dst, int* __restrict__ cnt) {
    int i = blockIdx.x * blockDim.x + threadIdx.x;
    if (i < NE) atomicAdd(&cnt[dst[i]], 1);
}

__global__ __launch_bounds__(1024) void scan_kernel(const int* __restrict__ cnt,
                                                    int* __restrict__ off,
                                                    int* __restrict__ cursor,
                                                    float* __restrict__ inv) {
    __shared__ int ps[1024];
    const int t = threadIdx.x;
    const int C = (NN + 1023) / 1024;
    const int base = t * C;
    int s = 0;
    for (int i = 0; i < C; ++i) {
        int idx = base + i;
        if (idx < NN) s += cnt[idx];
    }
    ps[t] = s;
    __syncthreads();
    for (int d = 1; d < 1024; d <<= 1) {
        int v = (t >= d) ? ps[t - d] : 0;
        __syncthreads();
        ps[t] += v;
        __syncthreads();
    }
    int run = (t == 0) ? 0 : ps[t - 1];
    for (int i = 0; i < C; ++i) {
        int idx = base + i;
        if (idx < NN) {
            int c = cnt[idx];
            off[idx] = run;
            cursor[idx] = run;
            inv[idx] = 1.0f / (float)max(c, 1);
            run += c;
        }
    }
}

__global__ void fill_kernel(const int* __restrict__ src, const int* __restrict__ dst,
                            int* __restrict__ cursor, int* __restrict__ srcs) {
    int e = blockIdx.x * blockDim.x + threadIdx.x;
    if (e < NE) {
        int p = atomicAdd(&cursor[dst[e]], 1);
        srcs[p] = src[e];
    }
}

// ---------------- pull-gather mean aggregation, one wave per dst node ----------------
// MODE: 0 = out = mean ; 1 = out = relu(pre + mean) ; 2 = out = pre + mean
template<int D, int MODE>
__global__ __launch_bounds__(256) void gather_kernel(
    const float* __restrict__ y, const int* __restrict__ srcs,
    const int* __restrict__ off, const int* __restrict__ cnt,
    const float* __restrict__ inv, const float* __restrict__ pre,
    float* __restrict__ out) {
    const int w = (blockIdx.x * blockDim.x + threadIdx.x) >> 6;
    const int lane = threadIdx.x & 63;
    if (w >= NN) return;
    const int o = uni(off[w]);
    const int n = uni(cnt[w]);
    float a0 = 0.0f, a1 = 0.0f;
    int i = 0;
    for (; i + 4 <= n; i += 4) {
        int sv[4];
#pragma unroll
        for (int u = 0; u < 4; ++u) sv[u] = srcs[o + i + u];
#pragma unroll
        for (int u = 0; u < 4; ++u) {
            a0 += y[(size_t)sv[u] * D + lane];
            if constexpr (D == 128) a1 += y[(size_t)sv[u] * D + 64 + lane];
        }
    }
    for (; i < n; ++i) {
        int s = srcs[o + i];
        a0 += y[(size_t)s * D + lane];
        if constexpr (D == 128) a1 += y[(size_t)s * D + 64 + lane];
    }
    const float iv = inv[w];
    const size_t b = (size_t)w * D + lane;
    float r0 = a0 * iv;
    if constexpr (MODE != 0) r0 += pre[b];
    if constexpr (MODE == 1) r0 = fmaxf(r0, 0.0f);
    out[b] = r0;
    if constexpr (D == 128) {
        float r1 = a1 * iv;
        if constexpr (MODE != 0) r1 += pre[b + 64];
        if constexpr (MODE == 1) r1 = fmaxf(r1, 0.0f);
        out[b + 64] = r1;
    }
}

// ---------------- weight-stationary scalar-broadcast GEMM (dual weight) ----------------
// outA[n][0..OH*64) = x[n] @ Wa^T ; outB[n][0..OH*64) = x[n] @ Wb^T + biasb
// One wave owns 64 output cols (W column in VGPRs); x rows stream via scalar loads.
template<int K, int OH>
__global__ __launch_bounds__(256) void gemm_dual(
    const float* __restrict__ x,
    const float* __restrict__ Wa, const float* __restrict__ Wb,
    const float* __restrict__ biasb,
    float* __restrict__ outA, float* __restrict__ outB) {
    constexpr int OG = 2 * OH;
    constexpr int OS = OH * 64;
    const int lane = threadIdx.x & 63;
    const int gw = uni((int)(blockIdx.x * (blockDim.x >> 6) + (threadIdx.x >> 6)));
    if (gw >= OG * NSTRIPES) return;
    const int og = gw % OG;
    const int stripe = gw / OG;
    const bool bside = og >= OH;
    const float* __restrict__ W = bside ? Wb : Wa;
    float* __restrict__ out = bside ? outB : outA;
    const int ocol = (bside ? og - OH : og) * 64 + lane;

    float w[K];
#pragma unroll
    for (int k = 0; k < K; k += 4) {
        const float4 t = *reinterpret_cast<const float4*>(&W[(size_t)ocol * K + k]);
        w[k] = t.x; w[k + 1] = t.y; w[k + 2] = t.z; w[k + 3] = t.w;
    }
    const float b = bside ? biasb[ocol] : 0.0f;

    const int n0 = stripe * NPW;
    const int nend = min(n0 + NPW, NN);
    for (int n = n0; n < nend; n += 4) {
        const float* __restrict__ p0 = x + (size_t)n * K;
        const float* __restrict__ p1 = x + (size_t)min(n + 1, NN - 1) * K;
        const float* __restrict__ p2 = x + (size_t)min(n + 2, NN - 1) * K;
        const float* __restrict__ p3 = x + (size_t)min(n + 3, NN - 1) * K;
        float a0 = b, a1 = b, a2 = b, a3 = b;
#pragma unroll
        for (int k = 0; k < K; k += 4) {
            const float4 v0 = *reinterpret_cast<const float4*>(p0 + k);
            const float4 v1 = *reinterpret_cast<const float4*>(p1 + k);
            const float4 v2 = *reinterpret_cast<const float4*>(p2 + k);
            const float4 v3 = *reinterpret_cast<const float4*>(p3 + k);
            a0 = fmaf(v0.x, w[k], a0); a0 = fmaf(v0.y, w[k + 1], a0);
            a0 = fmaf(v0.z, w[k + 2], a0); a0 = fmaf(v0.w, w[k + 3], a0);
            a1 = fmaf(v1.x, w[k], a1); a1 = fmaf(v1.y, w[k + 1], a1);
            a1 = fmaf(v1.z, w[k + 2], a1); a1 = fmaf(v1.w, w[k + 3], a1);
            a2 = fmaf(v2.x, w[k], a2); a2 = fmaf(v2.y, w[k + 1], a2);
            a2 = fmaf(v2.z, w[k + 2], a2); a2 = fmaf(v2.w, w[k + 3], a2);
            a3 = fmaf(v3.x, w[k], a3); a3 = fmaf(v3.y, w[k + 1], a3);
            a3 = fmaf(v3.z, w[k + 2], a3); a3 = fmaf(v3.w, w[k + 3], a3);
        }
        const size_t ob = (size_t)n * OS + ocol;
        out[ob] = a0;
        if (n + 1 < nend) out[ob + OS] = a1;
        if (n + 2 < nend) out[ob + 2 * OS] = a2;
        if (n + 3 < nend) out[ob + 3 * OS] = a3;
    }
}

// ---------------- layer-2 fused dense: out = relu(s@Wl^T + x@Wr^T + bl), K=64, O=128 ----------------
__global__ __launch_bounds__(256) void gemm2_ws(
    const float* __restrict__ s, const float* __restrict__ x,
    const float* __restrict__ Wl, const float* __restrict__ Wr,
    const float* __restrict__ bl, float* __restrict__ out) {
    constexpr int K = 64, OG = 2, OS = 128;
    const int lane = threadIdx.x & 63;
    const int gw = uni((int)(blockIdx.x * (blockDim.x >> 6) + (threadIdx.x >> 6)));
    if (gw >= OG * NSTRIPES) return;
    const int og = gw % OG;
    const int stripe = gw / OG;
    const int ocol = og * 64 + lane;

    float wl[K], wr[K];
#pragma unroll
    for (int k = 0; k < K; k += 4) {
        const float4 tl = *reinterpret_cast<const float4*>(&Wl[(size_t)ocol * K + k]);
        const float4 tr = *reinterpret_cast<const float4*>(&Wr[(size_t)ocol * K + k]);
        wl[k] = tl.x; wl[k + 1] = tl.y; wl[k + 2] = tl.z; wl[k + 3] = tl.w;
        wr[k] = tr.x; wr[k + 1] = tr.y; wr[k + 2] = tr.z; wr[k + 3] = tr.w;
    }
    const float b = bl[ocol];

    const int n0 = stripe * NPW;
    const int nend = min(n0 + NPW, NN);
    for (int n = n0; n < nend; n += 2) {
        const float* __restrict__ ps0 = s + (size_t)n * K;
        const float* __restrict__ px0 = x + (size_t)n * K;
        const float* __restrict__ ps1 = s + (size_t)min(n + 1, NN - 1) * K;
        const float* __restrict__ px1 = x + (size_t)min(n + 1, NN - 1) * K;
        float aS0 = b, aX0 = 0.0f, aS1 = b, aX1 = 0.0f;
#pragma unroll
        for (int k = 0; k < K; k += 4) {
            const float4 s0 = *reinterpret_cast<const float4*>(ps0 + k);
            const float4 x0 = *reinterpret_cast<const float4*>(px0 + k);
            const float4 s1 = *reinterpret_cast<const float4*>(ps1 + k);
            const float4 x1 = *reinterpret_cast<const float4*>(px1 + k);
            aS0 = fmaf(s0.x, wl[k], aS0); aS0 = fmaf(s0.y, wl[k + 1], aS0);
            aS0 = fmaf(s0.z, wl[k + 2], aS0); aS0 = fmaf(s0.w, wl[k + 3], aS0);
            aX0 = fmaf(x0.x, wr[k], aX0); aX0 = fmaf(x0.y, wr[k + 1], aX0);
            aX0 = fmaf(x0.z, wr[k + 2], aX0); aX0 = fmaf(x0.w, wr[k + 3], aX0);
            aS1 = fmaf(s1.x, wl[k], aS1); aS1 = fmaf(s1.y, wl[k + 1], aS1);
            aS1 = fmaf(s1.z, wl[k + 2], aS1); aS1 = fmaf(s1.w, wl[k + 3], aS1);
            aX1 = fmaf(x1.x, wr[k], aX1); aX1 = fmaf(x1.y, wr[k + 1], aX1);
            aX1 = fmaf(x1.z, wr[k + 2], aX1); aX1 = fmaf(x1.w, wr[k + 3], aX1);
        }
        const size_t ob = (size_t)n * OS + ocol;
        out[ob] = fmaxf(aS0 + aX0, 0.0f);
        if (n + 1 < nend) out[ob + OS] = fmaxf(aS1 + aX1, 0.0f);
    }
}

extern "C" void kernel_launch(void* const* d_in, const int* in_sizes, int n_in,
                              void* d_out, int out_size, void* d_ws, size_t ws_size,
                              hipStream_t stream) {
    const float* x   = (const float*)d_in[0];
    const int*   eix = (const int*)d_in[1];
    const float* Wl1 = (const float*)d_in[2];
    const float* bl1 = (const float*)d_in[3];
    const float* Wr1 = (const float*)d_in[4];
    const float* Wl2 = (const float*)d_in[5];
    const float* bl2 = (const float*)d_in[6];
    const float* Wr2 = (const float*)d_in[7];
    const float* Wl3 = (const float*)d_in[8];
    const float* bl3 = (const float*)d_in[9];
    const float* Wr3 = (const float*)d_in[10];
    const float* Wl4 = (const float*)d_in[11];
    const float* bl4 = (const float*)d_in[12];
    const float* Wr4 = (const float*)d_in[13];
    float* out = (float*)d_out;

    const int* src = eix;        // edge_index[0]
    const int* dst = eix + NE;   // edge_index[1]

    // workspace layout
    char* ws = (char*)d_ws;
    int*   cnt    = (int*)ws;                       // [NN]
    int*   off    = cnt + NN;                       // [NN]
    int*   cursor = off + NN;                       // [NN]
    float* inv    = (float*)(cursor + NN);          // [NN]
    int*   srcs   = (int*)(inv + NN);               // [NE]
    float* G1  = (float*)(srcs + NE);               // [NN*128]
    float* H13 = G1 + (size_t)NN * 128;             // [NN*128]
    float* H2  = H13 + (size_t)NN * 128;            // [NN*128]

    // ---- CSR build ----
    hipMemsetAsync(cnt, 0, NN * sizeof(int), stream);
    count_kernel<<<(NE + 255) / 256, 256, 0, stream>>>(dst, cnt);
    scan_kernel<<<1, 1024, 0, stream>>>(cnt, off, cursor, inv);
    fill_kernel<<<(NE + 255) / 256, 256, 0, stream>>>(src, dst, cursor, srcs);

    // ---- Layer 1 (128 -> 64, project-first) ----
    gemm_dual<128, 1><<<(2 * NSTRIPES + 3) / 4, 256, 0, stream>>>(x, Wl1, Wr1, bl1, G1, H13);
    gather_kernel<64, 1><<<12500, 256, 0, stream>>>(G1, srcs, off, cnt, inv, H13, H13);

    // ---- Layer 2 (64 -> 128, aggregate-first) ----
    gather_kernel<64, 0><<<12500, 256, 0, stream>>>(H13, srcs, off, cnt, inv, nullptr, G1);
    gemm2_ws<<<(2 * NSTRIPES + 3) / 4, 256, 0, stream>>>(G1, H13, Wl2, Wr2, bl2, H2);

    // ---- Layer 3 (128 -> 128, project-first) ----
    gemm_dual<128, 2><<<(4 * NSTRIPES + 3) / 4, 256, 0, stream>>>(H2, Wl3, Wr3, bl3, G1, H13);
    gather_kernel<128, 1><<<12500, 256, 0, stream>>>(G1, srcs, off, cnt, inv, H13, H13);

    // ---- Layer 4 (128 -> 64, project-first, into d_out) ----
    gemm_dual<128, 1><<<(2 * NSTRIPES + 3) / 4, 256, 0, stream>>>(H13, Wl4, Wr4, bl4, G1, out);
    gather_kernel<64, 2><<<12500, 256, 0, stream>>>(G1, srcs, off, cnt, inv, out, out);
}

// Round 5
// 809.192 us; speedup vs baseline: 2.0101x; 1.1753x over previous
//
#include <hip/hip_runtime.h>

#define NN 50000
#define NE 800000
#define NB 391            // ceil(NN/128) node-blocks, 128 nodes per block

__device__ __forceinline__ int uni(int v) { return __builtin_amdgcn_readfirstlane(v); }

// ---------------- CSR build: count, scan(+inv), bucket fill ----------------
__global__ void count_kernel(const int* __restrict__ dst, int* __restrict__ cnt) {
    int i = blockIdx.x * blockDim.x + threadIdx.x;
    if (i < NE) atomicAdd(&cnt[dst[i]], 1);
}

__global__ __launch_bounds__(1024) void scan_kernel(const int* __restrict__ cnt,
                                                    int* __restrict__ off,
                                                    int* __restrict__ cursor,
                                                    float* __restrict__ inv) {
    __shared__ int ps[1024];
    const int t = threadIdx.x;
    const int C = (NN + 1023) / 1024;
    const int base = t * C;
    int s = 0;
    for (int i = 0; i < C; ++i) {
        int idx = base + i;
        if (idx < NN) s += cnt[idx];
    }
    ps[t] = s;
    __syncthreads();
    for (int d = 1; d < 1024; d <<= 1) {
        int v = (t >= d) ? ps[t - d] : 0;
        __syncthreads();
        ps[t] += v;
        __syncthreads();
    }
    int run = (t == 0) ? 0 : ps[t - 1];
    for (int i = 0; i < C; ++i) {
        int idx = base + i;
        if (idx < NN) {
            int c = cnt[idx];
            off[idx] = run;
            cursor[idx] = run;
            inv[idx] = 1.0f / (float)max(c, 1);
            run += c;
        }
    }
}

__global__ void fill_kernel(const int* __restrict__ src, const int* __restrict__ dst,
                            int* __restrict__ cursor, int* __restrict__ srcs) {
    int e = blockIdx.x * blockDim.x + threadIdx.x;
    if (e < NE) {
        int p = atomicAdd(&cursor[dst[e]], 1);
        srcs[p] = src[e];
    }
}

// ---------------- pull-gather mean aggregation, one wave per dst node ----------------
// MODE: 0 = out = mean ; 1 = out = relu(pre + mean) ; 2 = out = pre + mean
template<int D, int MODE>
__global__ __launch_bounds__(256) void gather_kernel(
    const float* __restrict__ y, const int* __restrict__ srcs,
    const int* __restrict__ off, const int* __restrict__ cnt,
    const float* __restrict__ inv, const float* __restrict__ pre,
    float* __restrict__ out) {
    const int w = (blockIdx.x * blockDim.x + threadIdx.x) >> 6;
    const int lane = threadIdx.x & 63;
    if (w >= NN) return;
    const int o = uni(off[w]);
    const int n = uni(cnt[w]);
    float a0 = 0.0f, a1 = 0.0f;
    int i = 0;
    for (; i + 4 <= n; i += 4) {
        int sv[4];
#pragma unroll
        for (int u = 0; u < 4; ++u) sv[u] = srcs[o + i + u];
#pragma unroll
        for (int u = 0; u < 4; ++u) {
            a0 += y[(size_t)sv[u] * D + lane];
            if constexpr (D == 128) a1 += y[(size_t)sv[u] * D + 64 + lane];
        }
    }
    for (; i < n; ++i) {
        int s = srcs[o + i];
        a0 += y[(size_t)s * D + lane];
        if constexpr (D == 128) a1 += y[(size_t)s * D + 64 + lane];
    }
    const float iv = inv[w];
    const size_t b = (size_t)w * D + lane;
    float r0 = a0 * iv;
    if constexpr (MODE != 0) r0 += pre[b];
    if constexpr (MODE == 1) r0 = fmaxf(r0, 0.0f);
    out[b] = r0;
    if constexpr (D == 128) {
        float r1 = a1 * iv;
        if constexpr (MODE != 0) r1 += pre[b + 64];
        if constexpr (MODE == 1) r1 = fmaxf(r1, 0.0f);
        out[b + 64] = r1;
    }
}

// ---------------- LDS-broadcast weight-stationary GEMM (dual weight) ----------------
// Block: 4 waves, one 64-col output stripe of one weight side, 128 nodes.
// LDS holds W^T stripe as float4-per-k-quad; lanes broadcast-share it.
// outA[n] = x[n] @ Wa^T ; outB[n] = x[n] @ Wb^T + biasb
template<int K, int OH>
__global__ __launch_bounds__(256) void gemm_lds(
    const float* __restrict__ x,
    const float* __restrict__ Wa, const float* __restrict__ Wb,
    const float* __restrict__ biasb,
    float* __restrict__ outA, float* __restrict__ outB) {
    constexpr int OG = 2 * OH;       // total 64-col stripes across both sides
    constexpr int K4 = K / 4;
    __shared__ float4 wP[K4][64];

    const int og = (int)blockIdx.x % OG;
    const int nb = (int)blockIdx.x / OG;
    const bool bside = og >= OH;
    const float* __restrict__ W = bside ? Wb : Wa;
    float* __restrict__ out = bside ? outB : outA;
    const int obase = (bside ? og - OH : og) * 64;
    constexpr int OS = OH * 64;      // output row stride

    // stage W^T stripe: wP[k4][o] = {W[o][4k4..4k4+3]}
    for (int idx = threadIdx.x; idx < 64 * K4; idx += 256) {
        int o = idx / K4, k4 = idx % K4;
        wP[k4][o] = *reinterpret_cast<const float4*>(&W[(size_t)(obase + o) * K + k4 * 4]);
    }
    __syncthreads();

    const int lane = threadIdx.x & 63;
    const int wid = uni((int)threadIdx.x >> 6);
    const int ocol = obase + lane;
    const float b = bside ? biasb[ocol] : 0.0f;
    const int n0 = nb * 128 + wid * 32;

#pragma unroll 1
    for (int g = 0; g < 4; ++g) {
        const int n = n0 + g * 8;
        const float* xr[8];
#pragma unroll
        for (int j = 0; j < 8; ++j)
            xr[j] = x + (size_t)min(n + j, NN - 1) * K;
        float acc[8];
#pragma unroll
        for (int j = 0; j < 8; ++j) acc[j] = b;
#pragma unroll 2
        for (int k4 = 0; k4 < K4; ++k4) {
            const float4 wv = wP[k4][lane];
#pragma unroll
            for (int j = 0; j < 8; ++j) {
                const float4 xv = *reinterpret_cast<const float4*>(xr[j] + k4 * 4);
                acc[j] = fmaf(xv.x, wv.x, acc[j]);
                acc[j] = fmaf(xv.y, wv.y, acc[j]);
                acc[j] = fmaf(xv.z, wv.z, acc[j]);
                acc[j] = fmaf(xv.w, wv.w, acc[j]);
            }
        }
#pragma unroll
        for (int j = 0; j < 8; ++j) {
            if (n + j < NN) out[(size_t)(n + j) * OS + obase + lane] = acc[j];
        }
    }
}

// ---------------- layer-2 fused: out = relu(s@Wl^T + x@Wr^T + bl), K=64, O=128 ----------------
__global__ __launch_bounds__(256) void gemm2_lds(
    const float* __restrict__ s, const float* __restrict__ x,
    const float* __restrict__ Wl, const float* __restrict__ Wr,
    const float* __restrict__ bl, float* __restrict__ out) {
    constexpr int K = 64, K4 = K / 4, OS = 128;
    __shared__ float4 wlP[K4][64];
    __shared__ float4 wrP[K4][64];

    const int og = (int)blockIdx.x % 2;
    const int nb = (int)blockIdx.x / 2;
    const int obase = og * 64;

    for (int idx = threadIdx.x; idx < 64 * K4; idx += 256) {
        int o = idx / K4, k4 = idx % K4;
        wlP[k4][o] = *reinterpret_cast<const float4*>(&Wl[(size_t)(obase + o) * K + k4 * 4]);
        wrP[k4][o] = *reinterpret_cast<const float4*>(&Wr[(size_t)(obase + o) * K + k4 * 4]);
    }
    __syncthreads();

    const int lane = threadIdx.x & 63;
    const int wid = uni((int)threadIdx.x >> 6);
    const int ocol = obase + lane;
    const float b = bl[ocol];
    const int n0 = nb * 128 + wid * 32;

#pragma unroll 1
    for (int g = 0; g < 4; ++g) {
        const int n = n0 + g * 8;
        const float* sr[8];
        const float* xr[8];
#pragma unroll
        for (int j = 0; j < 8; ++j) {
            const size_t r = (size_t)min(n + j, NN - 1) * K;
            sr[j] = s + r;
            xr[j] = x + r;
        }
        float acc[8];
#pragma unroll
        for (int j = 0; j < 8; ++j) acc[j] = b;
#pragma unroll 2
        for (int k4 = 0; k4 < K4; ++k4) {
            const float4 lv = wlP[k4][lane];
            const float4 rv = wrP[k4][lane];
#pragma unroll
            for (int j = 0; j < 8; ++j) {
                const float4 sv = *reinterpret_cast<const float4*>(sr[j] + k4 * 4);
                const float4 xv = *reinterpret_cast<const float4*>(xr[j] + k4 * 4);
                acc[j] = fmaf(sv.x, lv.x, acc[j]);
                acc[j] = fmaf(sv.y, lv.y, acc[j]);
                acc[j] = fmaf(sv.z, lv.z, acc[j]);
                acc[j] = fmaf(sv.w, lv.w, acc[j]);
                acc[j] = fmaf(xv.x, rv.x, acc[j]);
                acc[j] = fmaf(xv.y, rv.y, acc[j]);
                acc[j] = fmaf(xv.z, rv.z, acc[j]);
                acc[j] = fmaf(xv.w, rv.w, acc[j]);
            }
        }
#pragma unroll
        for (int j = 0; j < 8; ++j) {
            if (n + j < NN) out[(size_t)(n + j) * OS + obase + lane] = fmaxf(acc[j], 0.0f);
        }
    }
}

extern "C" void kernel_launch(void* const* d_in, const int* in_sizes, int n_in,
                              void* d_out, int out_size, void* d_ws, size_t ws_size,
                              hipStream_t stream) {
    const float* x   = (const float*)d_in[0];
    const int*   eix = (const int*)d_in[1];
    const float* Wl1 = (const float*)d_in[2];
    const float* bl1 = (const float*)d_in[3];
    const float* Wr1 = (const float*)d_in[4];
    const float* Wl2 = (const float*)d_in[5];
    const float* bl2 = (const float*)d_in[6];
    const float* Wr2 = (const float*)d_in[7];
    const float* Wl3 = (const float*)d_in[8];
    const float* bl3 = (const float*)d_in[9];
    const float* Wr3 = (const float*)d_in[10];
    const float* Wl4 = (const float*)d_in[11];
    const float* bl4 = (const float*)d_in[12];
    const float* Wr4 = (const float*)d_in[13];
    float* out = (float*)d_out;

    const int* src = eix;        // edge_index[0]
    const int* dst = eix + NE;   // edge_index[1]

    // workspace layout
    char* ws = (char*)d_ws;
    int*   cnt    = (int*)ws;                       // [NN]
    int*   off    = cnt + NN;                       // [NN]
    int*   cursor = off + NN;                       // [NN]
    float* inv    = (float*)(cursor + NN);          // [NN]
    int*   srcs   = (int*)(inv + NN);               // [NE]
    float* G1  = (float*)(srcs + NE);               // [NN*128]
    float* H13 = G1 + (size_t)NN * 128;             // [NN*128]
    float* H2  = H13 + (size_t)NN * 128;            // [NN*128]

    // ---- CSR build ----
    hipMemsetAsync(cnt, 0, NN * sizeof(int), stream);
    count_kernel<<<(NE + 255) / 256, 256, 0, stream>>>(dst, cnt);
    scan_kernel<<<1, 1024, 0, stream>>>(cnt, off, cursor, inv);
    fill_kernel<<<(NE + 255) / 256, 256, 0, stream>>>(src, dst, cursor, srcs);

    // ---- Layer 1 (128 -> 64, project-first) ----
    gemm_lds<128, 1><<<2 * NB, 256, 0, stream>>>(x, Wl1, Wr1, bl1, G1, H13);
    gather_kernel<64, 1><<<12500, 256, 0, stream>>>(G1, srcs, off, cnt, inv, H13, H13);

    // ---- Layer 2 (64 -> 128, aggregate-first) ----
    gather_kernel<64, 0><<<12500, 256, 0, stream>>>(H13, srcs, off, cnt, inv, nullptr, G1);
    gemm2_lds<<<2 * NB, 256, 0, stream>>>(G1, H13, Wl2, Wr2, bl2, H2);

    // ---- Layer 3 (128 -> 128, project-first) ----
    gemm_lds<128, 2><<<4 * NB, 256, 0, stream>>>(H2, Wl3, Wr3, bl3, G1, H13);
    gather_kernel<128, 1><<<12500, 256, 0, stream>>>(G1, srcs, off, cnt, inv, H13, H13);

    // ---- Layer 4 (128 -> 64, project-first, into d_out) ----
    gemm_lds<128, 1><<<2 * NB, 256, 0, stream>>>(H13, Wl4, Wr4, bl4, G1, out);
    gather_kernel<64, 2><<<12500, 256, 0, stream>>>(G1, srcs, off, cnt, inv, out, out);
}

// Round 6
// 557.636 us; speedup vs baseline: 2.9169x; 1.4511x over previous
//
#include <hip/hip_runtime.h>

#define NN 50000
#define NE 800000
#define NBLK 196   // ceil(NN/256) node-blocks for gemm (256 nodes per block)

__device__ __forceinline__ int uni(int v) { return __builtin_amdgcn_readfirstlane(v); }

// ---------------- CSR build: count, scan(+inv), bucket fill ----------------
__global__ void count_kernel(const int* __restrict__ dst, int* __restrict__ cnt) {
    int i = blockIdx.x * blockDim.x + threadIdx.x;
    if (i < NE) atomicAdd(&cnt[dst[i]], 1);
}

__global__ __launch_bounds__(1024) void scan_kernel(const int* __restrict__ cnt,
                                                    int* __restrict__ off,
                                                    int* __restrict__ cursor,
                                                    float* __restrict__ inv) {
    __shared__ int ps[1024];
    const int t = threadIdx.x;
    const int C = (NN + 1023) / 1024;
    const int base = t * C;
    int s = 0;
    for (int i = 0; i < C; ++i) {
        int idx = base + i;
        if (idx < NN) s += cnt[idx];
    }
    ps[t] = s;
    __syncthreads();
    for (int d = 1; d < 1024; d <<= 1) {
        int v = (t >= d) ? ps[t - d] : 0;
        __syncthreads();
        ps[t] += v;
        __syncthreads();
    }
    int run = (t == 0) ? 0 : ps[t - 1];
    for (int i = 0; i < C; ++i) {
        int idx = base + i;
        if (idx < NN) {
            int c = cnt[idx];
            off[idx] = run;
            cursor[idx] = run;
            inv[idx] = 1.0f / (float)max(c, 1);
            run += c;
        }
    }
}

__global__ void fill_kernel(const int* __restrict__ src, const int* __restrict__ dst,
                            int* __restrict__ cursor, int* __restrict__ srcs) {
    int e = blockIdx.x * blockDim.x + threadIdx.x;
    if (e < NE) {
        int p = atomicAdd(&cursor[dst[e]], 1);
        srcs[p] = src[e];
    }
}

// ---------------- pull-gather mean aggregation, one wave per dst node ----------------
// MODE: 0 = out = mean ; 1 = out = relu(pre + mean) ; 2 = out = pre + mean
template<int D, int MODE>
__global__ __launch_bounds__(256) void gather_kernel(
    const float* __restrict__ y, const int* __restrict__ srcs,
    const int* __restrict__ off, const int* __restrict__ cnt,
    const float* __restrict__ inv, const float* __restrict__ pre,
    float* __restrict__ out) {
    const int w = (blockIdx.x * blockDim.x + threadIdx.x) >> 6;
    const int lane = threadIdx.x & 63;
    if (w >= NN) return;
    const int o = uni(off[w]);
    const int n = uni(cnt[w]);
    float a0 = 0.0f, a1 = 0.0f;
    int i = 0;
    for (; i + 4 <= n; i += 4) {
        int sv[4];
#pragma unroll
        for (int u = 0; u < 4; ++u) sv[u] = srcs[o + i + u];
#pragma unroll
        for (int u = 0; u < 4; ++u) {
            a0 += y[(size_t)sv[u] * D + lane];
            if constexpr (D == 128) a1 += y[(size_t)sv[u] * D + 64 + lane];
        }
    }
    for (; i < n; ++i) {
        int s = srcs[o + i];
        a0 += y[(size_t)s * D + lane];
        if constexpr (D == 128) a1 += y[(size_t)s * D + 64 + lane];
    }
    const float iv = inv[w];
    const size_t b = (size_t)w * D + lane;
    float r0 = a0 * iv;
    if constexpr (MODE != 0) r0 += pre[b];
    if constexpr (MODE == 1) r0 = fmaxf(r0, 0.0f);
    out[b] = r0;
    if constexpr (D == 128) {
        float r1 = a1 * iv;
        if constexpr (MODE != 0) r1 += pre[b + 64];
        if constexpr (MODE == 1) r1 = fmaxf(r1, 0.0f);
        out[b + 64] = r1;
    }
}

// ---------------- register-blocked outer-product GEMM ----------------
// Computes out[n][c] = sum_k in[n][k] * W[c][k] (+bias) for a 64-col stripe,
// 256 nodes per block. K=128 always; k<64 streams from in0, k>=64 from in1
// (pass in1 = in0+64 for a plain 128-wide input; for L2, in0/in1 are the two
// concatenated 64-wide inputs). Same split for W0/W1.
// Thread = 8 nodes x 8 cols of accumulators; both operands read from LDS
// transposed ([k][node], [k][col]) as broadcast-deduplicated b128 reads.
struct Stripes {
    const float* W0[4];
    const float* W1[4];
    const float* bias[4];
    float* out[4];
};

template<bool RELU>
__global__ __launch_bounds__(256) void gemm_rb(
    const float* __restrict__ in0, const float* __restrict__ in1,
    int rs0, int rs1, int ws0, int ws1, int OS, Stripes S) {
    __shared__ float wt[128][68];    // W^T stripe, padded
    __shared__ float xs[32][264];    // x panel transposed, padded

    const int t = threadIdx.x;
    const int y = blockIdx.y;
    const float* __restrict__ W0 = S.W0[y];
    const float* __restrict__ W1 = S.W1[y];
    const float* __restrict__ bias = S.bias[y];
    float* __restrict__ out = S.out[y];
    const int nb0 = (int)blockIdx.x * 256;

    // stage W^T: wt[k][c] = k<64 ? W0[c*ws0+k] : W1[c*ws1+k-64]
    for (int it = 0; it < 8; ++it) {
        int u = it * 256 + t;        // 0..2047
        int c = u >> 5;              // 0..63
        int kq = u & 31;             // 0..31
        const float* src = (kq < 16) ? (W0 + (size_t)c * ws0 + kq * 4)
                                     : (W1 + (size_t)c * ws1 + (kq - 16) * 4);
        float4 v = *reinterpret_cast<const float4*>(src);
        int k = kq * 4;
        wt[k][c] = v.x; wt[k + 1][c] = v.y; wt[k + 2][c] = v.z; wt[k + 3][c] = v.w;
    }

    const int lane = t & 63;
    const int wid = t >> 6;
    const int cg = lane & 7;
    const int ng = lane >> 3;
    const int nloc = wid * 64 + ng * 8;

    float acc[8][8];
#pragma unroll
    for (int i = 0; i < 8; ++i)
#pragma unroll
        for (int j = 0; j < 8; ++j) acc[i][j] = 0.0f;

#pragma unroll 1
    for (int p = 0; p < 4; ++p) {
        __syncthreads();
        {
            const float* __restrict__ src = (p < 2) ? in0 : in1;
            const int rs = (p < 2) ? rs0 : rs1;
            const int kb = (p & 1) * 32;
            for (int it = 0; it < 8; ++it) {
                int u = it * 256 + t;    // 0..2047
                int node = u >> 3;       // 0..255
                int kq = u & 7;          // 0..7
                int gn = min(nb0 + node, NN - 1);
                float4 v = *reinterpret_cast<const float4*>(src + (size_t)gn * rs + kb + kq * 4);
                int k = kq * 4;
                xs[k][node] = v.x; xs[k + 1][node] = v.y;
                xs[k + 2][node] = v.z; xs[k + 3][node] = v.w;
            }
        }
        __syncthreads();
#pragma unroll 4
        for (int kk = 0; kk < 32; ++kk) {
            float4 xa = *reinterpret_cast<const float4*>(&xs[kk][nloc]);
            float4 xb = *reinterpret_cast<const float4*>(&xs[kk][nloc + 4]);
            float4 wa = *reinterpret_cast<const float4*>(&wt[p * 32 + kk][cg * 8]);
            float4 wb = *reinterpret_cast<const float4*>(&wt[p * 32 + kk][cg * 8 + 4]);
            float xv[8] = {xa.x, xa.y, xa.z, xa.w, xb.x, xb.y, xb.z, xb.w};
            float wv[8] = {wa.x, wa.y, wa.z, wa.w, wb.x, wb.y, wb.z, wb.w};
#pragma unroll
            for (int i = 0; i < 8; ++i)
#pragma unroll
                for (int j = 0; j < 8; ++j)
                    acc[i][j] = fmaf(xv[i], wv[j], acc[i][j]);
        }
    }

    // epilogue
    float bv[8];
    if (bias) {
        float4 b0 = *reinterpret_cast<const float4*>(bias + cg * 8);
        float4 b1 = *reinterpret_cast<const float4*>(bias + cg * 8 + 4);
        bv[0] = b0.x; bv[1] = b0.y; bv[2] = b0.z; bv[3] = b0.w;
        bv[4] = b1.x; bv[5] = b1.y; bv[6] = b1.z; bv[7] = b1.w;
    } else {
#pragma unroll
        for (int j = 0; j < 8; ++j) bv[j] = 0.0f;
    }
#pragma unroll
    for (int i = 0; i < 8; ++i) {
        int n = nb0 + nloc + i;
        if (n < NN) {
            float r[8];
#pragma unroll
            for (int j = 0; j < 8; ++j) {
                r[j] = acc[i][j] + bv[j];
                if constexpr (RELU) r[j] = fmaxf(r[j], 0.0f);
            }
            float4 s0 = {r[0], r[1], r[2], r[3]};
            float4 s1 = {r[4], r[5], r[6], r[7]};
            *reinterpret_cast<float4*>(out + (size_t)n * OS + cg * 8) = s0;
            *reinterpret_cast<float4*>(out + (size_t)n * OS + cg * 8 + 4) = s1;
        }
    }
}

extern "C" void kernel_launch(void* const* d_in, const int* in_sizes, int n_in,
                              void* d_out, int out_size, void* d_ws, size_t ws_size,
                              hipStream_t stream) {
    const float* x   = (const float*)d_in[0];
    const int*   eix = (const int*)d_in[1];
    const float* Wl1 = (const float*)d_in[2];
    const float* bl1 = (const float*)d_in[3];
    const float* Wr1 = (const float*)d_in[4];
    const float* Wl2 = (const float*)d_in[5];
    const float* bl2 = (const float*)d_in[6];
    const float* Wr2 = (const float*)d_in[7];
    const float* Wl3 = (const float*)d_in[8];
    const float* bl3 = (const float*)d_in[9];
    const float* Wr3 = (const float*)d_in[10];
    const float* Wl4 = (const float*)d_in[11];
    const float* bl4 = (const float*)d_in[12];
    const float* Wr4 = (const float*)d_in[13];
    float* out = (float*)d_out;

    const int* src = eix;        // edge_index[0]
    const int* dst = eix + NE;   // edge_index[1]

    // workspace layout
    char* ws = (char*)d_ws;
    int*   cnt    = (int*)ws;                       // [NN]
    int*   off    = cnt + NN;                       // [NN]
    int*   cursor = off + NN;                       // [NN]
    float* inv    = (float*)(cursor + NN);          // [NN]
    int*   srcs   = (int*)(inv + NN);               // [NE]
    float* G1  = (float*)(srcs + NE);               // [NN*128]
    float* H13 = G1 + (size_t)NN * 128;             // [NN*128]
    float* H2  = H13 + (size_t)NN * 128;            // [NN*128]

    // ---- CSR build ----
    hipMemsetAsync(cnt, 0, NN * sizeof(int), stream);
    count_kernel<<<(NE + 255) / 256, 256, 0, stream>>>(dst, cnt);
    scan_kernel<<<1, 1024, 0, stream>>>(cnt, off, cursor, inv);
    fill_kernel<<<(NE + 255) / 256, 256, 0, stream>>>(src, dst, cursor, srcs);

    // ---- Layer 1 (128 -> 64, project-first) ----
    {
        Stripes s{};
        s.W0[0] = Wl1; s.W1[0] = Wl1 + 64; s.bias[0] = nullptr; s.out[0] = G1;
        s.W0[1] = Wr1; s.W1[1] = Wr1 + 64; s.bias[1] = bl1;     s.out[1] = H13;
        gemm_rb<false><<<dim3(NBLK, 2), 256, 0, stream>>>(x, x + 64, 128, 128, 128, 128, 64, s);
    }
    gather_kernel<64, 1><<<12500, 256, 0, stream>>>(G1, srcs, off, cnt, inv, H13, H13);

    // ---- Layer 2 (64 -> 128, aggregate-first, concat GEMM with fused relu) ----
    gather_kernel<64, 0><<<12500, 256, 0, stream>>>(H13, srcs, off, cnt, inv, nullptr, G1);
    {
        Stripes s{};
        s.W0[0] = Wl2;           s.W1[0] = Wr2;           s.bias[0] = bl2;      s.out[0] = H2;
        s.W0[1] = Wl2 + 64 * 64; s.W1[1] = Wr2 + 64 * 64; s.bias[1] = bl2 + 64; s.out[1] = H2 + 64;
        gemm_rb<true><<<dim3(NBLK, 2), 256, 0, stream>>>(G1, H13, 64, 64, 64, 64, 128, s);
    }

    // ---- Layer 3 (128 -> 128, project-first) ----
    {
        Stripes s{};
        s.W0[0] = Wl3;            s.W1[0] = Wl3 + 64;            s.bias[0] = nullptr;  s.out[0] = G1;
        s.W0[1] = Wl3 + 64 * 128; s.W1[1] = Wl3 + 64 * 128 + 64; s.bias[1] = nullptr;  s.out[1] = G1 + 64;
        s.W0[2] = Wr3;            s.W1[2] = Wr3 + 64;            s.bias[2] = bl3;      s.out[2] = H13;
        s.W0[3] = Wr3 + 64 * 128; s.W1[3] = Wr3 + 64 * 128 + 64; s.bias[3] = bl3 + 64; s.out[3] = H13 + 64;
        gemm_rb<false><<<dim3(NBLK, 4), 256, 0, stream>>>(H2, H2 + 64, 128, 128, 128, 128, 128, s);
    }
    gather_kernel<128, 1><<<12500, 256, 0, stream>>>(G1, srcs, off, cnt, inv, H13, H13);

    // ---- Layer 4 (128 -> 64, project-first, into d_out) ----
    {
        Stripes s{};
        s.W0[0] = Wl4; s.W1[0] = Wl4 + 64; s.bias[0] = nullptr; s.out[0] = G1;
        s.W0[1] = Wr4; s.W1[1] = Wr4 + 64; s.bias[1] = bl4;     s.out[1] = out;
        gemm_rb<false><<<dim3(NBLK, 2), 256, 0, stream>>>(H13, H13 + 64, 128, 128, 128, 128, 64, s);
    }
    gather_kernel<64, 2><<<12500, 256, 0, stream>>>(G1, srcs, off, cnt, inv, out, out);
}

// Round 7
// 419.142 us; speedup vs baseline: 3.8806x; 1.3304x over previous
//
#include <hip/hip_runtime.h>

#define NN 50000
#define NE 800000
#define NBLK 196   // ceil(NN/256) node-blocks for gemm (256 nodes per block)
#define SCB 196    // scan blocks (256 elems each)

__device__ __forceinline__ int uni(int v) { return __builtin_amdgcn_readfirstlane(v); }

// ---------------- CSR build: count, 3-phase scan(+inv), bucket fill ----------------
__global__ void count_kernel(const int* __restrict__ dst, int* __restrict__ cnt) {
    int i = blockIdx.x * blockDim.x + threadIdx.x;
    if (i < NE) atomicAdd(&cnt[dst[i]], 1);
}

// phase 1: per-block sums of cnt
__global__ __launch_bounds__(256) void scan1_kernel(const int* __restrict__ cnt,
                                                    int* __restrict__ part) {
    __shared__ int red[256];
    const int t = threadIdx.x;
    const int i = blockIdx.x * 256 + t;
    red[t] = (i < NN) ? cnt[i] : 0;
    __syncthreads();
#pragma unroll
    for (int d = 128; d > 0; d >>= 1) {
        if (t < d) red[t] += red[t + d];
        __syncthreads();
    }
    if (t == 0) part[blockIdx.x] = red[0];
}

// phase 2: exclusive scan of the SCB partials (single small block)
__global__ __launch_bounds__(256) void scan2_kernel(int* __restrict__ part) {
    __shared__ int ps[256];
    const int t = threadIdx.x;
    ps[t] = (t < SCB) ? part[t] : 0;
    __syncthreads();
#pragma unroll
    for (int d = 1; d < 256; d <<= 1) {
        int v = (t >= d) ? ps[t - d] : 0;
        __syncthreads();
        ps[t] += v;
        __syncthreads();
    }
    if (t < SCB) part[t] = (t == 0) ? 0 : ps[t - 1];
}

// phase 3: in-block scan + base; emit off, cursor, inv
__global__ __launch_bounds__(256) void scan3_kernel(const int* __restrict__ cnt,
                                                    const int* __restrict__ part,
                                                    int* __restrict__ off,
                                                    int* __restrict__ cursor,
                                                    float* __restrict__ inv) {
    __shared__ int ps[256];
    const int t = threadIdx.x;
    const int i = blockIdx.x * 256 + t;
    const int c = (i < NN) ? cnt[i] : 0;
    ps[t] = c;
    __syncthreads();
#pragma unroll
    for (int d = 1; d < 256; d <<= 1) {
        int v = (t >= d) ? ps[t - d] : 0;
        __syncthreads();
        ps[t] += v;
        __syncthreads();
    }
    if (i < NN) {
        const int o = part[blockIdx.x] + ps[t] - c;   // exclusive
        off[i] = o;
        cursor[i] = o;
        inv[i] = 1.0f / (float)max(c, 1);
    }
}

__global__ void fill_kernel(const int* __restrict__ src, const int* __restrict__ dst,
                            int* __restrict__ cursor, int* __restrict__ srcs) {
    int e = blockIdx.x * blockDim.x + threadIdx.x;
    if (e < NE) {
        int p = atomicAdd(&cursor[dst[e]], 1);
        srcs[p] = src[e];
    }
}

// ---------------- pull-gather mean aggregation, one wave per dst node ----------------
// MODE: 0 = out = mean ; 1 = out = relu(pre + mean) ; 2 = out = pre + mean
template<int D, int MODE>
__global__ __launch_bounds__(256) void gather_kernel(
    const float* __restrict__ y, const int* __restrict__ srcs,
    const int* __restrict__ off, const int* __restrict__ cnt,
    const float* __restrict__ inv, const float* __restrict__ pre,
    float* __restrict__ out) {
    const int w = (blockIdx.x * blockDim.x + threadIdx.x) >> 6;
    const int lane = threadIdx.x & 63;
    if (w >= NN) return;
    const int o = uni(off[w]);
    const int n = uni(cnt[w]);
    float a0 = 0.0f, a1 = 0.0f;
    int i = 0;
    for (; i + 4 <= n; i += 4) {
        int sv[4];
#pragma unroll
        for (int u = 0; u < 4; ++u) sv[u] = srcs[o + i + u];
#pragma unroll
        for (int u = 0; u < 4; ++u) {
            a0 += y[(size_t)sv[u] * D + lane];
            if constexpr (D == 128) a1 += y[(size_t)sv[u] * D + 64 + lane];
        }
    }
    for (; i < n; ++i) {
        int s = srcs[o + i];
        a0 += y[(size_t)s * D + lane];
        if constexpr (D == 128) a1 += y[(size_t)s * D + 64 + lane];
    }
    const float iv = inv[w];
    const size_t b = (size_t)w * D + lane;
    float r0 = a0 * iv;
    if constexpr (MODE != 0) r0 += pre[b];
    if constexpr (MODE == 1) r0 = fmaxf(r0, 0.0f);
    out[b] = r0;
    if constexpr (D == 128) {
        float r1 = a1 * iv;
        if constexpr (MODE != 0) r1 += pre[b + 64];
        if constexpr (MODE == 1) r1 = fmaxf(r1, 0.0f);
        out[b + 64] = r1;
    }
}

// ---------------- register-blocked outer-product GEMM ----------------
// out[n][c] = sum_k in[n][k] * W[c][k] (+bias) for a 64-col stripe, 256 nodes
// per block; K=128 split across in0/in1 (and W0/W1). Thread = 8x8 accumulators;
// operands from LDS transposed, broadcast-deduplicated b128 reads.
struct Stripes {
    const float* W0[4];
    const float* W1[4];
    const float* bias[4];
    float* out[4];
};

template<bool RELU>
__global__ __launch_bounds__(256) void gemm_rb(
    const float* __restrict__ in0, const float* __restrict__ in1,
    int rs0, int rs1, int ws0, int ws1, int OS, Stripes S) {
    __shared__ float wt[128][68];    // W^T stripe, padded
    __shared__ float xs[32][264];    // x panel transposed, padded

    const int t = threadIdx.x;
    const int y = blockIdx.y;
    const float* __restrict__ W0 = S.W0[y];
    const float* __restrict__ W1 = S.W1[y];
    const float* __restrict__ bias = S.bias[y];
    float* __restrict__ out = S.out[y];
    const int nb0 = (int)blockIdx.x * 256;

    // stage W^T: wt[k][c] = k<64 ? W0[c*ws0+k] : W1[c*ws1+k-64]
    for (int it = 0; it < 8; ++it) {
        int u = it * 256 + t;        // 0..2047
        int c = u >> 5;              // 0..63
        int kq = u & 31;             // 0..31
        const float* src = (kq < 16) ? (W0 + (size_t)c * ws0 + kq * 4)
                                     : (W1 + (size_t)c * ws1 + (kq - 16) * 4);
        float4 v = *reinterpret_cast<const float4*>(src);
        int k = kq * 4;
        wt[k][c] = v.x; wt[k + 1][c] = v.y; wt[k + 2][c] = v.z; wt[k + 3][c] = v.w;
    }

    const int lane = t & 63;
    const int wid = t >> 6;
    const int cg = lane & 7;
    const int ng = lane >> 3;
    const int nloc = wid * 64 + ng * 8;

    float acc[8][8];
#pragma unroll
    for (int i = 0; i < 8; ++i)
#pragma unroll
        for (int j = 0; j < 8; ++j) acc[i][j] = 0.0f;

#pragma unroll 1
    for (int p = 0; p < 4; ++p) {
        __syncthreads();
        {
            const float* __restrict__ src = (p < 2) ? in0 : in1;
            const int rs = (p < 2) ? rs0 : rs1;
            const int kb = (p & 1) * 32;
            for (int it = 0; it < 8; ++it) {
                int u = it * 256 + t;    // 0..2047
                int node = u >> 3;       // 0..255
                int kq = u & 7;          // 0..7
                int gn = min(nb0 + node, NN - 1);
                float4 v = *reinterpret_cast<const float4*>(src + (size_t)gn * rs + kb + kq * 4);
                int k = kq * 4;
                xs[k][node] = v.x; xs[k + 1][node] = v.y;
                xs[k + 2][node] = v.z; xs[k + 3][node] = v.w;
            }
        }
        __syncthreads();
#pragma unroll 4
        for (int kk = 0; kk < 32; ++kk) {
            float4 xa = *reinterpret_cast<const float4*>(&xs[kk][nloc]);
            float4 xb = *reinterpret_cast<const float4*>(&xs[kk][nloc + 4]);
            float4 wa = *reinterpret_cast<const float4*>(&wt[p * 32 + kk][cg * 8]);
            float4 wb = *reinterpret_cast<const float4*>(&wt[p * 32 + kk][cg * 8 + 4]);
            float xv[8] = {xa.x, xa.y, xa.z, xa.w, xb.x, xb.y, xb.z, xb.w};
            float wv[8] = {wa.x, wa.y, wa.z, wa.w, wb.x, wb.y, wb.z, wb.w};
#pragma unroll
            for (int i = 0; i < 8; ++i)
#pragma unroll
                for (int j = 0; j < 8; ++j)
                    acc[i][j] = fmaf(xv[i], wv[j], acc[i][j]);
        }
    }

    // epilogue
    float bv[8];
    if (bias) {
        float4 b0 = *reinterpret_cast<const float4*>(bias + cg * 8);
        float4 b1 = *reinterpret_cast<const float4*>(bias + cg * 8 + 4);
        bv[0] = b0.x; bv[1] = b0.y; bv[2] = b0.z; bv[3] = b0.w;
        bv[4] = b1.x; bv[5] = b1.y; bv[6] = b1.z; bv[7] = b1.w;
    } else {
#pragma unroll
        for (int j = 0; j < 8; ++j) bv[j] = 0.0f;
    }
#pragma unroll
    for (int i = 0; i < 8; ++i) {
        int n = nb0 + nloc + i;
        if (n < NN) {
            float r[8];
#pragma unroll
            for (int j = 0; j < 8; ++j) {
                r[j] = acc[i][j] + bv[j];
                if constexpr (RELU) r[j] = fmaxf(r[j], 0.0f);
            }
            float4 s0 = {r[0], r[1], r[2], r[3]};
            float4 s1 = {r[4], r[5], r[6], r[7]};
            *reinterpret_cast<float4*>(out + (size_t)n * OS + cg * 8) = s0;
            *reinterpret_cast<float4*>(out + (size_t)n * OS + cg * 8 + 4) = s1;
        }
    }
}

extern "C" void kernel_launch(void* const* d_in, const int* in_sizes, int n_in,
                              void* d_out, int out_size, void* d_ws, size_t ws_size,
                              hipStream_t stream) {
    const float* x   = (const float*)d_in[0];
    const int*   eix = (const int*)d_in[1];
    const float* Wl1 = (const float*)d_in[2];
    const float* bl1 = (const float*)d_in[3];
    const float* Wr1 = (const float*)d_in[4];
    const float* Wl2 = (const float*)d_in[5];
    const float* bl2 = (const float*)d_in[6];
    const float* Wr2 = (const float*)d_in[7];
    const float* Wl3 = (const float*)d_in[8];
    const float* bl3 = (const float*)d_in[9];
    const float* Wr3 = (const float*)d_in[10];
    const float* Wl4 = (const float*)d_in[11];
    const float* bl4 = (const float*)d_in[12];
    const float* Wr4 = (const float*)d_in[13];
    float* out = (float*)d_out;

    const int* src = eix;        // edge_index[0]
    const int* dst = eix + NE;   // edge_index[1]

    // workspace layout
    char* ws = (char*)d_ws;
    int*   cnt    = (int*)ws;                       // [NN]
    int*   off    = cnt + NN;                       // [NN]
    int*   cursor = off + NN;                       // [NN]
    float* inv    = (float*)(cursor + NN);          // [NN]
    int*   part   = (int*)(inv + NN);               // [256]
    int*   srcs   = part + 256;                     // [NE]
    float* G1  = (float*)(srcs + NE);               // [NN*128]
    float* H13 = G1 + (size_t)NN * 128;             // [NN*128]
    float* H2  = H13 + (size_t)NN * 128;            // [NN*128]

    // ---- CSR build ----
    hipMemsetAsync(cnt, 0, NN * sizeof(int), stream);
    count_kernel<<<(NE + 255) / 256, 256, 0, stream>>>(dst, cnt);
    scan1_kernel<<<SCB, 256, 0, stream>>>(cnt, part);
    scan2_kernel<<<1, 256, 0, stream>>>(part);
    scan3_kernel<<<SCB, 256, 0, stream>>>(cnt, part, off, cursor, inv);
    fill_kernel<<<(NE + 255) / 256, 256, 0, stream>>>(src, dst, cursor, srcs);

    // ---- Layer 1 (128 -> 64, project-first) ----
    {
        Stripes s{};
        s.W0[0] = Wl1; s.W1[0] = Wl1 + 64; s.bias[0] = nullptr; s.out[0] = G1;
        s.W0[1] = Wr1; s.W1[1] = Wr1 + 64; s.bias[1] = bl1;     s.out[1] = H13;
        gemm_rb<false><<<dim3(NBLK, 2), 256, 0, stream>>>(x, x + 64, 128, 128, 128, 128, 64, s);
    }
    gather_kernel<64, 1><<<12500, 256, 0, stream>>>(G1, srcs, off, cnt, inv, H13, H13);

    // ---- Layer 2 (64 -> 128, aggregate-first, concat GEMM with fused relu) ----
    gather_kernel<64, 0><<<12500, 256, 0, stream>>>(H13, srcs, off, cnt, inv, nullptr, G1);
    {
        Stripes s{};
        s.W0[0] = Wl2;           s.W1[0] = Wr2;           s.bias[0] = bl2;      s.out[0] = H2;
        s.W0[1] = Wl2 + 64 * 64; s.W1[1] = Wr2 + 64 * 64; s.bias[1] = bl2 + 64; s.out[1] = H2 + 64;
        gemm_rb<true><<<dim3(NBLK, 2), 256, 0, stream>>>(G1, H13, 64, 64, 64, 64, 128, s);
    }

    // ---- Layer 3 (128 -> 128, project-first) ----
    {
        Stripes s{};
        s.W0[0] = Wl3;            s.W1[0] = Wl3 + 64;            s.bias[0] = nullptr;  s.out[0] = G1;
        s.W0[1] = Wl3 + 64 * 128; s.W1[1] = Wl3 + 64 * 128 + 64; s.bias[1] = nullptr;  s.out[1] = G1 + 64;
        s.W0[2] = Wr3;            s.W1[2] = Wr3 + 64;            s.bias[2] = bl3;      s.out[2] = H13;
        s.W0[3] = Wr3 + 64 * 128; s.W1[3] = Wr3 + 64 * 128 + 64; s.bias[3] = bl3 + 64; s.out[3] = H13 + 64;
        gemm_rb<false><<<dim3(NBLK, 4), 256, 0, stream>>>(H2, H2 + 64, 128, 128, 128, 128, 128, s);
    }
    gather_kernel<128, 1><<<12500, 256, 0, stream>>>(G1, srcs, off, cnt, inv, H13, H13);

    // ---- Layer 4 (128 -> 64, project-first, into d_out) ----
    {
        Stripes s{};
        s.W0[0] = Wl4; s.W1[0] = Wl4 + 64; s.bias[0] = nullptr; s.out[0] = G1;
        s.W0[1] = Wr4; s.W1[1] = Wr4 + 64; s.bias[1] = bl4;     s.out[1] = out;
        gemm_rb<false><<<dim3(NBLK, 2), 256, 0, stream>>>(H13, H13 + 64, 128, 128, 128, 128, 64, s);
    }
    gather_kernel<64, 2><<<12500, 256, 0, stream>>>(G1, srcs, off, cnt, inv, out, out);
}

// Round 8
// 393.663 us; speedup vs baseline: 4.1318x; 1.0647x over previous
//
#include <hip/hip_runtime.h>

#define NN 50000
#define NE 800000
#define NBLK 196   // ceil(NN/256) node-blocks for gemm (256 nodes per block)
#define SCB 196    // scan blocks (256 elems each)

__device__ __forceinline__ int uni(int v) { return __builtin_amdgcn_readfirstlane(v); }

// ---------------- CSR build: count, 3-phase scan(+inv), bucket fill ----------------
__global__ void count_kernel(const int* __restrict__ dst, int* __restrict__ cnt) {
    int i = blockIdx.x * blockDim.x + threadIdx.x;
    if (i < NE) atomicAdd(&cnt[dst[i]], 1);
}

__global__ __launch_bounds__(256) void scan1_kernel(const int* __restrict__ cnt,
                                                    int* __restrict__ part) {
    __shared__ int red[256];
    const int t = threadIdx.x;
    const int i = blockIdx.x * 256 + t;
    red[t] = (i < NN) ? cnt[i] : 0;
    __syncthreads();
#pragma unroll
    for (int d = 128; d > 0; d >>= 1) {
        if (t < d) red[t] += red[t + d];
        __syncthreads();
    }
    if (t == 0) part[blockIdx.x] = red[0];
}

__global__ __launch_bounds__(256) void scan2_kernel(int* __restrict__ part) {
    __shared__ int ps[256];
    const int t = threadIdx.x;
    ps[t] = (t < SCB) ? part[t] : 0;
    __syncthreads();
#pragma unroll
    for (int d = 1; d < 256; d <<= 1) {
        int v = (t >= d) ? ps[t - d] : 0;
        __syncthreads();
        ps[t] += v;
        __syncthreads();
    }
    if (t < SCB) part[t] = (t == 0) ? 0 : ps[t - 1];
}

__global__ __launch_bounds__(256) void scan3_kernel(const int* __restrict__ cnt,
                                                    const int* __restrict__ part,
                                                    int* __restrict__ off,
                                                    int* __restrict__ cursor,
                                                    float* __restrict__ inv) {
    __shared__ int ps[256];
    const int t = threadIdx.x;
    const int i = blockIdx.x * 256 + t;
    const int c = (i < NN) ? cnt[i] : 0;
    ps[t] = c;
    __syncthreads();
#pragma unroll
    for (int d = 1; d < 256; d <<= 1) {
        int v = (t >= d) ? ps[t - d] : 0;
        __syncthreads();
        ps[t] += v;
        __syncthreads();
    }
    if (i < NN) {
        const int o = part[blockIdx.x] + ps[t] - c;   // exclusive
        off[i] = o;
        cursor[i] = o;
        inv[i] = 1.0f / (float)max(c, 1);
    }
}

__global__ void fill_kernel(const int* __restrict__ src, const int* __restrict__ dst,
                            int* __restrict__ cursor, int* __restrict__ srcs) {
    int e = blockIdx.x * blockDim.x + threadIdx.x;
    if (e < NE) {
        int p = atomicAdd(&cursor[dst[e]], 1);
        srcs[p] = src[e];
    }
}

// ---------------- pull-gather mean aggregation, one wave per dst node ----------------
// MODE: 0 = out = mean ; 1 = out = relu(pre + mean) ; 2 = out = pre + mean
template<int D, int MODE>
__global__ __launch_bounds__(256) void gather_kernel(
    const float* __restrict__ y, const int* __restrict__ srcs,
    const int* __restrict__ off, const int* __restrict__ cnt,
    const float* __restrict__ inv, const float* __restrict__ pre,
    float* __restrict__ out) {
    const int w = (blockIdx.x * blockDim.x + threadIdx.x) >> 6;
    const int lane = threadIdx.x & 63;
    if (w >= NN) return;
    const int o = uni(off[w]);
    const int n = uni(cnt[w]);
    float a0 = 0.0f, a1 = 0.0f;
    int i = 0;
    for (; i + 4 <= n; i += 4) {
        int sv[4];
#pragma unroll
        for (int u = 0; u < 4; ++u) sv[u] = srcs[o + i + u];
#pragma unroll
        for (int u = 0; u < 4; ++u) {
            a0 += y[(size_t)sv[u] * D + lane];
            if constexpr (D == 128) a1 += y[(size_t)sv[u] * D + 64 + lane];
        }
    }
    for (; i < n; ++i) {
        int s = srcs[o + i];
        a0 += y[(size_t)s * D + lane];
        if constexpr (D == 128) a1 += y[(size_t)s * D + 64 + lane];
    }
    const float iv = inv[w];
    const size_t b = (size_t)w * D + lane;
    float r0 = a0 * iv;
    if constexpr (MODE != 0) r0 += pre[b];
    if constexpr (MODE == 1) r0 = fmaxf(r0, 0.0f);
    out[b] = r0;
    if constexpr (D == 128) {
        float r1 = a1 * iv;
        if constexpr (MODE != 0) r1 += pre[b + 64];
        if constexpr (MODE == 1) r1 = fmaxf(r1, 0.0f);
        out[b + 64] = r1;
    }
}

// ---------------- register-blocked outer-product GEMM, conflict-free staging ----------------
// out[n][c] = sum_k in[n][k] * W[c][k] (+bias) for a 64-col stripe, 256 nodes/block.
// K=128 in four 32-k panels; per panel both W^T[32][68] and x^T[32][260] are staged
// with bank-engineered lane mappings (<=2-way on every LDS access).
struct Stripes {
    const float* W0[4];
    const float* W1[4];
    const float* bias[4];
    float* out[4];
};

template<bool RELU>
__global__ __launch_bounds__(256, 3) void gemm_rb(
    const float* __restrict__ in0, const float* __restrict__ in1,
    int rs0, int rs1, int ws0, int ws1, int OS, Stripes S) {
    __shared__ float wt[32][68];     // W^T panel; stride 68 = 4 mod 32
    __shared__ float xs[32][260];    // x^T panel; stride 260 = 4 mod 32

    const int t = threadIdx.x;
    const int y = blockIdx.y;
    const float* __restrict__ W0 = S.W0[y];
    const float* __restrict__ W1 = S.W1[y];
    const float* __restrict__ bias = S.bias[y];
    float* __restrict__ out = S.out[y];
    const int nb0 = (int)blockIdx.x * 256;

    const int lane = t & 63;
    const int wid = t >> 6;
    const int cg = lane & 7;
    const int ng = lane >> 3;
    const int nloc = wid * 64 + ng * 8;

    float acc[8][8];
#pragma unroll
    for (int i = 0; i < 8; ++i)
#pragma unroll
        for (int j = 0; j < 8; ++j) acc[i][j] = 0.0f;

#pragma unroll 1
    for (int p = 0; p < 4; ++p) {
        __syncthreads();
        // ---- stage W^T panel: wt[kl][c], kl = panel-local k (0..31) ----
        {
            const float* __restrict__ Wsel = (p < 2) ? W0 : W1;
            const int wssel = (p < 2) ? ws0 : ws1;
            const int kbw = (p & 1) * 32;
#pragma unroll
            for (int it = 0; it < 2; ++it) {
                int u = it * 256 + t;            // 0..511
                int kq = u & 3;                  // bank spread with c
                int c = (u >> 2) & 63;
                int k4 = ((u >> 8) << 2) + kq;   // 0..7
                float4 v = *reinterpret_cast<const float4*>(
                    Wsel + (size_t)c * wssel + kbw + k4 * 4);
                int kl = k4 * 4;
                wt[kl][c] = v.x; wt[kl + 1][c] = v.y;
                wt[kl + 2][c] = v.z; wt[kl + 3][c] = v.w;
            }
        }
        // ---- stage x^T panel: xs[kl][node] ----
        {
            const float* __restrict__ src = (p < 2) ? in0 : in1;
            const int rs = (p < 2) ? rs0 : rs1;
            const int kb = (p & 1) * 32;
#pragma unroll
            for (int it = 0; it < 8; ++it) {
                int u = it * 256 + t;                              // 0..2047
                int node = (u & 15) | (((u >> 7) & 15) << 4);      // 0..255
                int kq = ((u >> 4) & 3) | (((u >> 6) & 1) << 2);   // 0..7
                int gn = min(nb0 + node, NN - 1);
                float4 v = *reinterpret_cast<const float4*>(
                    src + (size_t)gn * rs + kb + kq * 4);
                int kl = kq * 4;
                xs[kl][node] = v.x; xs[kl + 1][node] = v.y;
                xs[kl + 2][node] = v.z; xs[kl + 3][node] = v.w;
            }
        }
        __syncthreads();
        // ---- compute: 32 k-steps, 8x8 outer product per thread ----
#pragma unroll 4
        for (int kk = 0; kk < 32; ++kk) {
            float4 xa = *reinterpret_cast<const float4*>(&xs[kk][nloc]);
            float4 xb = *reinterpret_cast<const float4*>(&xs[kk][nloc + 4]);
            float4 wa = *reinterpret_cast<const float4*>(&wt[kk][cg * 8]);
            float4 wb = *reinterpret_cast<const float4*>(&wt[kk][cg * 8 + 4]);
            float xv[8] = {xa.x, xa.y, xa.z, xa.w, xb.x, xb.y, xb.z, xb.w};
            float wv[8] = {wa.x, wa.y, wa.z, wa.w, wb.x, wb.y, wb.z, wb.w};
#pragma unroll
            for (int i = 0; i < 8; ++i)
#pragma unroll
                for (int j = 0; j < 8; ++j)
                    acc[i][j] = fmaf(xv[i], wv[j], acc[i][j]);
        }
    }

    // epilogue
    float bv[8];
    if (bias) {
        float4 b0 = *reinterpret_cast<const float4*>(bias + cg * 8);
        float4 b1 = *reinterpret_cast<const float4*>(bias + cg * 8 + 4);
        bv[0] = b0.x; bv[1] = b0.y; bv[2] = b0.z; bv[3] = b0.w;
        bv[4] = b1.x; bv[5] = b1.y; bv[6] = b1.z; bv[7] = b1.w;
    } else {
#pragma unroll
        for (int j = 0; j < 8; ++j) bv[j] = 0.0f;
    }
#pragma unroll
    for (int i = 0; i < 8; ++i) {
        int n = nb0 + nloc + i;
        if (n < NN) {
            float r[8];
#pragma unroll
            for (int j = 0; j < 8; ++j) {
                r[j] = acc[i][j] + bv[j];
                if constexpr (RELU) r[j] = fmaxf(r[j], 0.0f);
            }
            float4 s0 = {r[0], r[1], r[2], r[3]};
            float4 s1 = {r[4], r[5], r[6], r[7]};
            *reinterpret_cast<float4*>(out + (size_t)n * OS + cg * 8) = s0;
            *reinterpret_cast<float4*>(out + (size_t)n * OS + cg * 8 + 4) = s1;
        }
    }
}

extern "C" void kernel_launch(void* const* d_in, const int* in_sizes, int n_in,
                              void* d_out, int out_size, void* d_ws, size_t ws_size,
                              hipStream_t stream) {
    const float* x   = (const float*)d_in[0];
    const int*   eix = (const int*)d_in[1];
    const float* Wl1 = (const float*)d_in[2];
    const float* bl1 = (const float*)d_in[3];
    const float* Wr1 = (const float*)d_in[4];
    const float* Wl2 = (const float*)d_in[5];
    const float* bl2 = (const float*)d_in[6];
    const float* Wr2 = (const float*)d_in[7];
    const float* Wl3 = (const float*)d_in[8];
    const float* bl3 = (const float*)d_in[9];
    const float* Wr3 = (const float*)d_in[10];
    const float* Wl4 = (const float*)d_in[11];
    const float* bl4 = (const float*)d_in[12];
    const float* Wr4 = (const float*)d_in[13];
    float* out = (float*)d_out;

    const int* src = eix;        // edge_index[0]
    const int* dst = eix + NE;   // edge_index[1]

    // workspace layout
    char* ws = (char*)d_ws;
    int*   cnt    = (int*)ws;                       // [NN]
    int*   off    = cnt + NN;                       // [NN]
    int*   cursor = off + NN;                       // [NN]
    float* inv    = (float*)(cursor + NN);          // [NN]
    int*   part   = (int*)(inv + NN);               // [256]
    int*   srcs   = part + 256;                     // [NE]
    float* G1  = (float*)(srcs + NE);               // [NN*128]
    float* H13 = G1 + (size_t)NN * 128;             // [NN*128]
    float* H2  = H13 + (size_t)NN * 128;            // [NN*128]

    // ---- CSR build ----
    hipMemsetAsync(cnt, 0, NN * sizeof(int), stream);
    count_kernel<<<(NE + 255) / 256, 256, 0, stream>>>(dst, cnt);
    scan1_kernel<<<SCB, 256, 0, stream>>>(cnt, part);
    scan2_kernel<<<1, 256, 0, stream>>>(part);
    scan3_kernel<<<SCB, 256, 0, stream>>>(cnt, part, off, cursor, inv);
    fill_kernel<<<(NE + 255) / 256, 256, 0, stream>>>(src, dst, cursor, srcs);

    // ---- Layer 1 (128 -> 64, project-first) ----
    {
        Stripes s{};
        s.W0[0] = Wl1; s.W1[0] = Wl1 + 64; s.bias[0] = nullptr; s.out[0] = G1;
        s.W0[1] = Wr1; s.W1[1] = Wr1 + 64; s.bias[1] = bl1;     s.out[1] = H13;
        gemm_rb<false><<<dim3(NBLK, 2), 256, 0, stream>>>(x, x + 64, 128, 128, 128, 128, 64, s);
    }
    gather_kernel<64, 1><<<12500, 256, 0, stream>>>(G1, srcs, off, cnt, inv, H13, H13);

    // ---- Layer 2 (64 -> 128, aggregate-first, concat GEMM with fused relu) ----
    gather_kernel<64, 0><<<12500, 256, 0, stream>>>(H13, srcs, off, cnt, inv, nullptr, G1);
    {
        Stripes s{};
        s.W0[0] = Wl2;           s.W1[0] = Wr2;           s.bias[0] = bl2;      s.out[0] = H2;
        s.W0[1] = Wl2 + 64 * 64; s.W1[1] = Wr2 + 64 * 64; s.bias[1] = bl2 + 64; s.out[1] = H2 + 64;
        gemm_rb<true><<<dim3(NBLK, 2), 256, 0, stream>>>(G1, H13, 64, 64, 64, 64, 128, s);
    }

    // ---- Layer 3 (128 -> 128, project-first) ----
    {
        Stripes s{};
        s.W0[0] = Wl3;            s.W1[0] = Wl3 + 64;            s.bias[0] = nullptr;  s.out[0] = G1;
        s.W0[1] = Wl3 + 64 * 128; s.W1[1] = Wl3 + 64 * 128 + 64; s.bias[1] = nullptr;  s.out[1] = G1 + 64;
        s.W0[2] = Wr3;            s.W1[2] = Wr3 + 64;            s.bias[2] = bl3;      s.out[2] = H13;
        s.W0[3] = Wr3 + 64 * 128; s.W1[3] = Wr3 + 64 * 128 + 64; s.bias[3] = bl3 + 64; s.out[3] = H13 + 64;
        gemm_rb<false><<<dim3(NBLK, 4), 256, 0, stream>>>(H2, H2 + 64, 128, 128, 128, 128, 128, s);
    }
    gather_kernel<128, 1><<<12500, 256, 0, stream>>>(G1, srcs, off, cnt, inv, H13, H13);

    // ---- Layer 4 (128 -> 64, project-first, into d_out) ----
    {
        Stripes s{};
        s.W0[0] = Wl4; s.W1[0] = Wl4 + 64; s.bias[0] = nullptr; s.out[0] = G1;
        s.W0[1] = Wr4; s.W1[1] = Wr4 + 64; s.bias[1] = bl4;     s.out[1] = out;
        gemm_rb<false><<<dim3(NBLK, 2), 256, 0, stream>>>(H13, H13 + 64, 128, 128, 128, 128, 64, s);
    }
    gather_kernel<64, 2><<<12500, 256, 0, stream>>>(G1, srcs, off, cnt, inv, out, out);
}

// Round 9
// 392.584 us; speedup vs baseline: 4.1432x; 1.0027x over previous
//
#include <hip/hip_runtime.h>

#define NN 50000
#define NE 800000
#define SCB 196    // scan blocks (256 elems each)
#define GB 391     // ceil(NN/128) gemm node-blocks

typedef __attribute__((ext_vector_type(8))) short short8v;
typedef __attribute__((ext_vector_type(4))) float float4v;

__device__ __forceinline__ int uni(int v) { return __builtin_amdgcn_readfirstlane(v); }

// ---------------- CSR build: count, 3-phase scan(+inv), bucket fill ----------------
__global__ void count_kernel(const int* __restrict__ dst, int* __restrict__ cnt) {
    int i = blockIdx.x * blockDim.x + threadIdx.x;
    if (i < NE) atomicAdd(&cnt[dst[i]], 1);
}

__global__ __launch_bounds__(256) void scan1_kernel(const int* __restrict__ cnt,
                                                    int* __restrict__ part) {
    __shared__ int red[256];
    const int t = threadIdx.x;
    const int i = blockIdx.x * 256 + t;
    red[t] = (i < NN) ? cnt[i] : 0;
    __syncthreads();
#pragma unroll
    for (int d = 128; d > 0; d >>= 1) {
        if (t < d) red[t] += red[t + d];
        __syncthreads();
    }
    if (t == 0) part[blockIdx.x] = red[0];
}

__global__ __launch_bounds__(256) void scan2_kernel(int* __restrict__ part) {
    __shared__ int ps[256];
    const int t = threadIdx.x;
    ps[t] = (t < SCB) ? part[t] : 0;
    __syncthreads();
#pragma unroll
    for (int d = 1; d < 256; d <<= 1) {
        int v = (t >= d) ? ps[t - d] : 0;
        __syncthreads();
        ps[t] += v;
        __syncthreads();
    }
    if (t < SCB) part[t] = (t == 0) ? 0 : ps[t - 1];
}

__global__ __launch_bounds__(256) void scan3_kernel(const int* __restrict__ cnt,
                                                    const int* __restrict__ part,
                                                    int* __restrict__ off,
                                                    int* __restrict__ cursor,
                                                    float* __restrict__ inv) {
    __shared__ int ps[256];
    const int t = threadIdx.x;
    const int i = blockIdx.x * 256 + t;
    const int c = (i < NN) ? cnt[i] : 0;
    ps[t] = c;
    __syncthreads();
#pragma unroll
    for (int d = 1; d < 256; d <<= 1) {
        int v = (t >= d) ? ps[t - d] : 0;
        __syncthreads();
        ps[t] += v;
        __syncthreads();
    }
    if (i < NN) {
        const int o = part[blockIdx.x] + ps[t] - c;   // exclusive
        off[i] = o;
        cursor[i] = o;
        inv[i] = 1.0f / (float)max(c, 1);
    }
}

__global__ void fill_kernel(const int* __restrict__ src, const int* __restrict__ dst,
                            int* __restrict__ cursor, int* __restrict__ srcs) {
    int e = blockIdx.x * blockDim.x + threadIdx.x;
    if (e < NE) {
        int p = atomicAdd(&cursor[dst[e]], 1);
        srcs[p] = src[e];
    }
}

// ---------------- pull-gather mean aggregation, one wave per dst node ----------------
// MODE: 0 = out = mean ; 1 = out = relu(pre + mean) ; 2 = out = pre + mean
// ys/ps/os: row strides of y/pre/out.
template<int D, int MODE>
__global__ __launch_bounds__(256) void gather_kernel(
    const float* __restrict__ y, int ys, const int* __restrict__ srcs,
    const int* __restrict__ off, const int* __restrict__ cnt,
    const float* __restrict__ inv, const float* __restrict__ pre, int ps,
    float* __restrict__ out, int os) {
    const int w = (blockIdx.x * blockDim.x + threadIdx.x) >> 6;
    const int lane = threadIdx.x & 63;
    if (w >= NN) return;
    const int o = uni(off[w]);
    const int n = uni(cnt[w]);
    float a0 = 0.0f, a1 = 0.0f;
    int i = 0;
    for (; i + 4 <= n; i += 4) {
        int sv[4];
#pragma unroll
        for (int u = 0; u < 4; ++u) sv[u] = srcs[o + i + u];
#pragma unroll
        for (int u = 0; u < 4; ++u) {
            a0 += y[(size_t)sv[u] * ys + lane];
            if constexpr (D == 128) a1 += y[(size_t)sv[u] * ys + 64 + lane];
        }
    }
    for (; i < n; ++i) {
        int s = srcs[o + i];
        a0 += y[(size_t)s * ys + lane];
        if constexpr (D == 128) a1 += y[(size_t)s * ys + 64 + lane];
    }
    const float iv = inv[w];
    float r0 = a0 * iv;
    if constexpr (MODE != 0) r0 += pre[(size_t)w * ps + lane];
    if constexpr (MODE == 1) r0 = fmaxf(r0, 0.0f);
    out[(size_t)w * os + lane] = r0;
    if constexpr (D == 128) {
        float r1 = a1 * iv;
        if constexpr (MODE != 0) r1 += pre[(size_t)w * ps + 64 + lane];
        if constexpr (MODE == 1) r1 = fmaxf(r1, 0.0f);
        out[(size_t)w * os + 64 + lane] = r1;
    }
}

// ---------------- weight plane build: fp32 -> bf16 hi/lo (truncation split) ----------------
// 5 segments of [128][128]: seg0=[Wl1;Wr1] seg1=[Wl2|Wr2] seg2=Wl3 seg3=Wr3 seg4=[Wl4;Wr4]
struct WSrc { const float* p[8]; };

__global__ __launch_bounds__(256) void wplanes_kernel(WSrc S,
                                                      unsigned short* __restrict__ ph,
                                                      unsigned short* __restrict__ pl) {
    const int e = blockIdx.x * 256 + threadIdx.x;   // 0..16383
    const int seg = blockIdx.y;
    const int row = e >> 7, k = e & 127;
    float x;
    switch (seg) {
        case 0:  x = (row < 64) ? S.p[0][row * 128 + k] : S.p[1][(row - 64) * 128 + k]; break;
        case 1:  x = (k < 64)   ? S.p[2][row * 64 + k]  : S.p[3][row * 64 + (k - 64)];  break;
        case 2:  x = S.p[4][e]; break;
        case 3:  x = S.p[5][e]; break;
        default: x = (row < 64) ? S.p[6][row * 128 + k] : S.p[7][(row - 64) * 128 + k]; break;
    }
    const unsigned u = __float_as_uint(x);
    const float lo = x - __uint_as_float(u & 0xFFFF0000u);
    const int o = seg * 16384 + e;
    ph[o] = (unsigned short)(u >> 16);
    pl[o] = (unsigned short)(__float_as_uint(lo) >> 16);
}

// ---------------- MFMA split-bf16 GEMM ----------------
// out[n][c] = sum_k in[n][k] * Wplane[c][k] (+bias), K=128, 128 cols per launch.
// Block: 4 waves (2 node-halves x 2 col-halves), tile 128 nodes x 128 cols.
// Wave: 4x4 frags of 16x16 via mfma_f32_16x16x32_bf16, 3 precision terms
// (Ah*Bh + Ah*Bl + Al*Bh). No LDS. A split in-register from fp32.
__global__ __launch_bounds__(256) void gemm_mfma(
    const float* __restrict__ in,
    const unsigned short* __restrict__ Bh, const unsigned short* __restrict__ Bl,
    float* __restrict__ out0, const float* __restrict__ bias0, int os0,
    float* __restrict__ out1, const float* __restrict__ bias1, int os1,
    int relu) {
    const int t = threadIdx.x;
    const int lane = t & 63;
    const int wid = t >> 6;
    const int wn = wid & 1;          // node half
    const int wc = wid >> 1;         // col half
    const int l15 = lane & 15;
    const int lk = lane >> 4;        // 0..3 k-octet
    const int nb = (int)blockIdx.x * 128 + wn * 64;

    float* const outp = wc ? out1 : out0;
    const float* const biasp = wc ? bias1 : bias0;
    const int os = wc ? os1 : os0;
    const unsigned short* const Bhp = Bh + (size_t)(wc * 64) * 128;
    const unsigned short* const Blp = Bl + (size_t)(wc * 64) * 128;

    float4v acc[4][4];
#pragma unroll
    for (int mi = 0; mi < 4; ++mi)
#pragma unroll
        for (int ci = 0; ci < 4; ++ci) acc[mi][ci] = (float4v)0.0f;

    const float* arow[4];
#pragma unroll
    for (int mi = 0; mi < 4; ++mi) {
        int r = nb + mi * 16 + l15;
        if (r > NN - 1) r = NN - 1;
        arow[mi] = in + (size_t)r * 128;
    }
    const unsigned short* brow[4];
#pragma unroll
    for (int ci = 0; ci < 4; ++ci) brow[ci] = Bhp + (size_t)(ci * 16 + l15) * 128;

    for (int ks = 0; ks < 4; ++ks) {
        const int ko = ks * 32 + lk * 8;
        short8v Ah[4], Al[4];
#pragma unroll
        for (int mi = 0; mi < 4; ++mi) {
            const float4v v0 = *reinterpret_cast<const float4v*>(arow[mi] + ko);
            const float4v v1 = *reinterpret_cast<const float4v*>(arow[mi] + ko + 4);
            float xv[8] = {v0.x, v0.y, v0.z, v0.w, v1.x, v1.y, v1.z, v1.w};
            union { unsigned u[4]; short8v s; } H, L;
#pragma unroll
            for (int q = 0; q < 4; ++q) {
                const unsigned u0 = __float_as_uint(xv[2 * q]);
                const unsigned u1 = __float_as_uint(xv[2 * q + 1]);
                const float l0 = xv[2 * q]     - __uint_as_float(u0 & 0xFFFF0000u);
                const float l1 = xv[2 * q + 1] - __uint_as_float(u1 & 0xFFFF0000u);
                H.u[q] = (u1 & 0xFFFF0000u) | (u0 >> 16);
                L.u[q] = (__float_as_uint(l1) & 0xFFFF0000u) | (__float_as_uint(l0) >> 16);
            }
            Ah[mi] = H.s;
            Al[mi] = L.s;
        }
        short8v Bhf[4], Blf[4];
#pragma unroll
        for (int ci = 0; ci < 4; ++ci) {
            Bhf[ci] = *reinterpret_cast<const short8v*>(brow[ci] + ko);
            Blf[ci] = *reinterpret_cast<const short8v*>(brow[ci] + (Blp - Bhp) + ko);
        }
#pragma unroll
        for (int mi = 0; mi < 4; ++mi)
#pragma unroll
            for (int ci = 0; ci < 4; ++ci) {
                acc[mi][ci] = __builtin_amdgcn_mfma_f32_16x16x32_bf16(Ah[mi], Bhf[ci], acc[mi][ci], 0, 0, 0);
                acc[mi][ci] = __builtin_amdgcn_mfma_f32_16x16x32_bf16(Ah[mi], Blf[ci], acc[mi][ci], 0, 0, 0);
                acc[mi][ci] = __builtin_amdgcn_mfma_f32_16x16x32_bf16(Al[mi], Bhf[ci], acc[mi][ci], 0, 0, 0);
            }
    }

    // epilogue: C/D map col=lane&15, row=(lane>>4)*4+j
#pragma unroll
    for (int ci = 0; ci < 4; ++ci) {
        const int c = ci * 16 + l15;
        const float b = biasp ? biasp[c] : 0.0f;
#pragma unroll
        for (int mi = 0; mi < 4; ++mi) {
#pragma unroll
            for (int j = 0; j < 4; ++j) {
                const int r = nb + mi * 16 + lk * 4 + j;
                if (r < NN) {
                    float v = acc[mi][ci][j] + b;
                    if (relu) v = fmaxf(v, 0.0f);
                    outp[(size_t)r * os + c] = v;
                }
            }
        }
    }
}

extern "C" void kernel_launch(void* const* d_in, const int* in_sizes, int n_in,
                              void* d_out, int out_size, void* d_ws, size_t ws_size,
                              hipStream_t stream) {
    const float* x   = (const float*)d_in[0];
    const int*   eix = (const int*)d_in[1];
    const float* Wl1 = (const float*)d_in[2];
    const float* bl1 = (const float*)d_in[3];
    const float* Wr1 = (const float*)d_in[4];
    const float* Wl2 = (const float*)d_in[5];
    const float* bl2 = (const float*)d_in[6];
    const float* Wr2 = (const float*)d_in[7];
    const float* Wl3 = (const float*)d_in[8];
    const float* bl3 = (const float*)d_in[9];
    const float* Wr3 = (const float*)d_in[10];
    const float* Wl4 = (const float*)d_in[11];
    const float* bl4 = (const float*)d_in[12];
    const float* Wr4 = (const float*)d_in[13];
    float* out = (float*)d_out;

    const int* src = eix;        // edge_index[0]
    const int* dst = eix + NE;   // edge_index[1]

    // workspace layout
    char* ws = (char*)d_ws;
    int*   cnt    = (int*)ws;                        // [NN]
    int*   off    = cnt + NN;                        // [NN]
    int*   cursor = off + NN;                        // [NN]
    float* inv    = (float*)(cursor + NN);           // [NN]
    int*   part   = (int*)(inv + NN);                // [256]
    int*   srcs   = part + 256;                      // [NE]
    unsigned short* ph = (unsigned short*)(srcs + NE);   // [81920]
    unsigned short* pl = ph + 81920;                     // [81920]
    float* HCAT = (float*)(pl + 81920);              // [NN*128]  [mean | h1], later G3, later G1(L4)
    float* H2   = HCAT + (size_t)NN * 128;           // [NN*128]
    float* HPRE = H2 + (size_t)NN * 128;             // [NN*128]  G1(L1), later h3pre/h3

    // ---- CSR build ----
    hipMemsetAsync(cnt, 0, NN * sizeof(int), stream);
    count_kernel<<<(NE + 255) / 256, 256, 0, stream>>>(dst, cnt);
    scan1_kernel<<<SCB, 256, 0, stream>>>(cnt, part);
    scan2_kernel<<<1, 256, 0, stream>>>(part);
    scan3_kernel<<<SCB, 256, 0, stream>>>(cnt, part, off, cursor, inv);
    fill_kernel<<<(NE + 255) / 256, 256, 0, stream>>>(src, dst, cursor, srcs);

    // ---- weight bf16 hi/lo planes ----
    {
        WSrc s;
        s.p[0] = Wl1; s.p[1] = Wr1; s.p[2] = Wl2; s.p[3] = Wr2;
        s.p[4] = Wl3; s.p[5] = Wr3; s.p[6] = Wl4; s.p[7] = Wr4;
        wplanes_kernel<<<dim3(64, 5), 256, 0, stream>>>(s, ph, pl);
    }

    // ---- Layer 1: gemm x@[Wl1;Wr1] -> G1(=HPRE, os64), h1pre(=HCAT+64, os128, +bl1) ----
    gemm_mfma<<<GB, 256, 0, stream>>>(x, ph, pl,
                                      HPRE, nullptr, 64,
                                      HCAT + 64, bl1, 128, 0);
    gather_kernel<64, 1><<<12500, 256, 0, stream>>>(HPRE, 64, srcs, off, cnt, inv,
                                                    HCAT + 64, 128, HCAT + 64, 128);

    // ---- Layer 2: mean into HCAT cols 0..63, then [mean|h1]@[Wl2|Wr2] -> H2 (relu) ----
    gather_kernel<64, 0><<<12500, 256, 0, stream>>>(HCAT + 64, 128, srcs, off, cnt, inv,
                                                    nullptr, 0, HCAT, 128);
    gemm_mfma<<<GB, 256, 0, stream>>>(HCAT, ph + 16384, pl + 16384,
                                      H2, bl2, 128,
                                      H2 + 64, bl2 + 64, 128, 1);

    // ---- Layer 3: h2@Wl3 -> G3(=HCAT), h2@Wr3+bl3 -> h3pre(=HPRE); gather -> h3(=HPRE) ----
    gemm_mfma<<<GB, 256, 0, stream>>>(H2, ph + 2 * 16384, pl + 2 * 16384,
                                      HCAT, nullptr, 128,
                                      HCAT + 64, nullptr, 128, 0);
    gemm_mfma<<<GB, 256, 0, stream>>>(H2, ph + 3 * 16384, pl + 3 * 16384,
                                      HPRE, bl3, 128,
                                      HPRE + 64, bl3 + 64, 128, 0);
    gather_kernel<128, 1><<<12500, 256, 0, stream>>>(HCAT, 128, srcs, off, cnt, inv,
                                                     HPRE, 128, HPRE, 128);

    // ---- Layer 4: h3@[Wl4;Wr4] -> G1(=HCAT, os64), outpre(=d_out, +bl4); gather -> out ----
    gemm_mfma<<<GB, 256, 0, stream>>>(HPRE, ph + 4 * 16384, pl + 4 * 16384,
                                      HCAT, nullptr, 64,
                                      out, bl4, 64, 0);
    gather_kernel<64, 2><<<12500, 256, 0, stream>>>(HCAT, 64, srcs, off, cnt, inv,
                                                    out, 64, out, 64);
}